// Round 3
// baseline (831.018 us; speedup 1.0000x reference)
//
#include <hip/hip_runtime.h>
#include <hip/hip_bf16.h>

// MonetMoVDE: B=4 T=2048 D=2048 H=8 E=512 M=8, F=4096, HALF=1024
#define TOK   8192   // B*T
#define DD    2048
#define FF    4096
#define EE    512
#define HALF  1024
#define KCAT  8704   // F + F + E  (concat K for V-GEMMs, 8704 = 136*64)

typedef __bf16 bf16x8 __attribute__((ext_vector_type(8)));
typedef __bf16 bf16x4 __attribute__((ext_vector_type(4)));
typedef float  f32x4  __attribute__((ext_vector_type(4)));
typedef float  f32x16 __attribute__((ext_vector_type(16)));
using bf16 = __hip_bfloat16;

#define AS1(p) ((const __attribute__((address_space(1))) void*)(p))
#define AS3(p) ((__attribute__((address_space(3))) void*)(p))

// ---------------- prep kernels ----------------

__global__ void cvt_bf16(const float* __restrict__ in, bf16* __restrict__ out, int n4) {
    int i = blockIdx.x * blockDim.x + threadIdx.x;
    int stride = gridDim.x * blockDim.x;
    for (; i < n4; i += stride) {
        float4 v = ((const float4*)in)[i];
        bf16x4 o;
        o[0] = (__bf16)v.x; o[1] = (__bf16)v.y; o[2] = (__bf16)v.z; o[3] = (__bf16)v.w;
        ((bf16x4*)out)[i] = o;
    }
}

// W [1024][8704] = [vA | vB | bT]   (vA,vB: [1024][4096] f32; bmat: [512][1024] f32)
__global__ void pack_w(const float* __restrict__ vA, const float* __restrict__ vB,
                       const float* __restrict__ bmat, bf16* __restrict__ W) {
    int n = blockIdx.x;
    const float* ra = vA + (size_t)n * FF;
    const float* rb = vB + (size_t)n * FF;
    bf16* w = W + (size_t)n * KCAT;
    for (int k = threadIdx.x; k < FF; k += 256) {
        w[k]      = __float2bfloat16(ra[k]);
        w[FF + k] = __float2bfloat16(rb[k]);
    }
    for (int e = threadIdx.x; e < EE; e += 256)
        w[2 * FF + e] = __float2bfloat16(bmat[(size_t)e * HALF + n]);
}

// ---------------- GEMM: C[m,n] = sum_k A[m,k] * Bw[n,k] ----------------
// 256x256 tile, BK=64, 8 waves (2Mx4N), 32x32x16 bf16 MFMA, per-wave C 128x64.
// LDS per buffer (64KB): A01 @0, A23 @16K, B01 @32K, B23 @48K; sub-tile =
// 256 rows x 32 K-elems (64B rows), XOR swizzle byte ^= ((row&3)<<4).
// 4 phases per K-tile (kk=0..3); phase q stages sub-tile q of tile t+1 into
// the other buffer; vmcnt(4) at odd-phase ends (counted, never 0 mid-loop).
// Fused dual-GEMM; MODE 0: fp32 store, MODE 1: relu(z+bias)^2 -> bf16 store.
template<int MODE>
__global__ __launch_bounds__(512, 2)
void gemm32(const bf16* __restrict__ A0, const bf16* __restrict__ B0,
            const float* __restrict__ bias0, void* __restrict__ C0,
            const bf16* __restrict__ A1, const bf16* __restrict__ B1,
            const float* __restrict__ bias1, void* __restrict__ C1,
            int nbm, int nbn, int K, int ldc)
{
    __shared__ __align__(16) char smem[131072];   // 2 x 64KB
    const int tid  = threadIdx.x;
    const int lane = tid & 63;
    const int wid  = tid >> 6;
    const int wm = wid >> 2, wn = wid & 3;
    const int ln31 = lane & 31, kb = lane >> 5;

    int bid = blockIdx.x;
    {   // bijective XCD swizzle (m204)
        int nwg = gridDim.x;
        int q = nwg >> 3, r = nwg & 7;
        int xcd = bid & 7, idx = bid >> 3;
        bid = (xcd < r ? xcd * (q + 1) : r * (q + 1) + (xcd - r) * q) + idx;
    }
    const int npg = nbm * nbn;
    const int g   = bid / npg;
    const int lb  = bid - g * npg;
    const int bm = lb / nbn, bn = lb - bm * nbn;

    const bf16*  A    = g ? A1 : A0;
    const bf16*  Bw   = g ? B1 : B0;
    const float* bias = g ? bias1 : bias0;
    char* Cout = (char*)(g ? C1 : C0);

    const long row0 = (long)bm * 256;
    const int  col0 = bn * 256;
    const int  nt   = K >> 6;

    // staging sources (pre-swizzled; involution) + linear LDS dest offsets
    const char* gA[2]; const char* gB[2];
    uint32_t ldst0, ldst1;
    #pragma unroll
    for (int l = 0; l < 2; ++l) {
        const uint32_t S = (uint32_t)(l * 512 + tid) * 16;
        const int r  = (int)(S >> 6);                       // sub-tile row 0..255
        const int cb = (int)((S & 63) ^ ((uint32_t)(r & 3) << 4));
        gA[l] = (const char*)A + (row0 + r) * (long)K * 2 + cb;
        gB[l] = (const char*)Bw + (long)(col0 + r) * K * 2 + cb;
    }
    ldst0 = (uint32_t)(tid & ~63) * 16;
    ldst1 = 8192u + (uint32_t)(tid & ~63) * 16;

    // per-lane LDS read offsets (within sub-tile)
    const uint32_t aB = (uint32_t)(wm * 128 + ln31) * 64;
    const uint32_t bB = 32768u + (uint32_t)(wn * 64 + ln31) * 64;
    const uint32_t coffE = (uint32_t)((kb ^ (lane & 3)) << 4);        // even phase (kkL=0)
    const uint32_t coffO = (uint32_t)(((kb | 2) ^ (lane & 3)) << 4);  // odd phase  (kkL=1)

    f32x16 acc[4][2];
    #pragma unroll
    for (int i = 0; i < 4; ++i)
        #pragma unroll
        for (int j = 0; j < 2; ++j)
            acc[i][j] = (f32x16)(0.f);

    // prologue: stage tile 0 into buf0 (order A01,B01,A23,B23)
    __builtin_amdgcn_global_load_lds(AS1(gA[0]),      AS3(smem +     0 + ldst0), 16, 0, 0);
    __builtin_amdgcn_global_load_lds(AS1(gA[1]),      AS3(smem +     0 + ldst1), 16, 0, 0);
    __builtin_amdgcn_global_load_lds(AS1(gB[0]),      AS3(smem + 32768 + ldst0), 16, 0, 0);
    __builtin_amdgcn_global_load_lds(AS1(gB[1]),      AS3(smem + 32768 + ldst1), 16, 0, 0);
    __builtin_amdgcn_global_load_lds(AS1(gA[0] + 64), AS3(smem + 16384 + ldst0), 16, 0, 0);
    __builtin_amdgcn_global_load_lds(AS1(gA[1] + 64), AS3(smem + 16384 + ldst1), 16, 0, 0);
    __builtin_amdgcn_global_load_lds(AS1(gB[0] + 64), AS3(smem + 49152 + ldst0), 16, 0, 0);
    __builtin_amdgcn_global_load_lds(AS1(gB[1] + 64), AS3(smem + 49152 + ldst1), 16, 0, 0);
    asm volatile("s_waitcnt vmcnt(4)\n\ts_barrier" ::: "memory");

#define MFMA8()                                                                        \
    __builtin_amdgcn_s_setprio(1);                                                     \
    acc[0][0] = __builtin_amdgcn_mfma_f32_32x32x16_bf16(a0, b0, acc[0][0], 0, 0, 0);   \
    acc[0][1] = __builtin_amdgcn_mfma_f32_32x32x16_bf16(a0, b1, acc[0][1], 0, 0, 0);   \
    acc[1][0] = __builtin_amdgcn_mfma_f32_32x32x16_bf16(a1, b0, acc[1][0], 0, 0, 0);   \
    acc[1][1] = __builtin_amdgcn_mfma_f32_32x32x16_bf16(a1, b1, acc[1][1], 0, 0, 0);   \
    acc[2][0] = __builtin_amdgcn_mfma_f32_32x32x16_bf16(a2, b0, acc[2][0], 0, 0, 0);   \
    acc[2][1] = __builtin_amdgcn_mfma_f32_32x32x16_bf16(a2, b1, acc[2][1], 0, 0, 0);   \
    acc[3][0] = __builtin_amdgcn_mfma_f32_32x32x16_bf16(a3, b0, acc[3][0], 0, 0, 0);   \
    acc[3][1] = __builtin_amdgcn_mfma_f32_32x32x16_bf16(a3, b1, acc[3][1], 0, 0, 0);   \
    __builtin_amdgcn_s_setprio(0);

#define PHASE(Q, LOFF, COFFv)                                                          \
    {                                                                                  \
        if (st) {                                                                      \
            __builtin_amdgcn_global_load_lds(                                          \
                AS1(((Q & 1) ? gB : gA)[0] + koff + (Q >> 1) * 64),                    \
                AS3(pt + LOFF + ldst0), 16, 0, 0);                                     \
            __builtin_amdgcn_global_load_lds(                                          \
                AS1(((Q & 1) ? gB : gA)[1] + koff + (Q >> 1) * 64),                    \
                AS3(pt + LOFF + ldst1), 16, 0, 0);                                     \
        }                                                                              \
        const char* ps = pb + (Q >> 1) * 16384;                                        \
        bf16x8 a0 = *(const bf16x8*)(ps + aB + COFFv);                                 \
        bf16x8 a1 = *(const bf16x8*)(ps + aB + 2048 + COFFv);                          \
        bf16x8 a2 = *(const bf16x8*)(ps + aB + 4096 + COFFv);                          \
        bf16x8 a3 = *(const bf16x8*)(ps + aB + 6144 + COFFv);                          \
        bf16x8 b0 = *(const bf16x8*)(ps + bB + COFFv);                                 \
        bf16x8 b1 = *(const bf16x8*)(ps + bB + 2048 + COFFv);                          \
        asm volatile("s_barrier" ::: "memory");                                        \
        MFMA8();                                                                       \
    }

    for (int t = 0; t < nt; ++t) {
        char* pb = smem + (t & 1) * 65536;
        char* pt = smem + ((t + 1) & 1) * 65536;
        const bool st = (t + 1 < nt);
        const long koff = (long)(t + 1) * 128;

        PHASE(0, 0, coffE)
        asm volatile("s_barrier" ::: "memory");
        PHASE(1, 32768, coffO)
        if (st) asm volatile("s_waitcnt vmcnt(4)" ::: "memory");
        else    asm volatile("s_waitcnt vmcnt(0)" ::: "memory");
        asm volatile("s_barrier" ::: "memory");
        PHASE(2, 16384, coffE)
        asm volatile("s_barrier" ::: "memory");
        PHASE(3, 49152, coffO)
        if (st) asm volatile("s_waitcnt vmcnt(4)" ::: "memory");
        asm volatile("s_barrier" ::: "memory");
    }
#undef PHASE
#undef MFMA8

    // epilogue: 32x32 C/D layout: col = ln31, row = (rg&3) + 8*(rg>>2) + 4*kb
    const int rowb = wm * 128 + kb * 4;
    const int colb = col0 + wn * 64 + ln31;
    #pragma unroll
    for (int i = 0; i < 4; ++i) {
        #pragma unroll
        for (int j = 0; j < 2; ++j) {
            const int cc = colb + j * 32;
            float badd = 0.f;
            if (MODE == 1) badd = bias[cc];
            #pragma unroll
            for (int rg = 0; rg < 16; ++rg) {
                long row = row0 + rowb + i * 32 + (rg & 3) + 8 * (rg >> 2);
                float v = acc[i][j][rg];
                if (MODE == 1) {
                    v += badd;
                    v = fmaxf(v, 0.f);
                    v = v * v;
                    ((bf16*)Cout)[row * ldc + cc] = __float2bfloat16(v);
                } else {
                    ((float*)Cout)[row * ldc + cc] = v;
                }
            }
        }
    }
}

// ---------------- glue: per-token gating / tiny einsums ----------------
// In:  g1,g2 [TOK][8][512] f32; Yl[:,0:4096]=x1 raw bf16; Yr[:,4096:8192]=x2 raw bf16
// Out: Yl = [x1*g1s | y12 | g1s]; Yr = [y21 | x2*g2s | g2s]  (all bf16)
#define GPAD 524   // 8-row pad: h-stride hits 8 distinct banks; 524*4%16==0
__global__ __launch_bounds__(256)
void glue(const float* __restrict__ g1, const float* __restrict__ g2,
          bf16* __restrict__ Yl, bf16* __restrict__ Yr)
{
    __shared__ __align__(16) float g1t[8 * GPAD];
    __shared__ __align__(16) float g2t[8 * GPAD];
    __shared__ float g1s[EE], g2s[EE];
    __shared__ float t1s[64], t2s[64];
    __shared__ float t1p[4][64], t2p[4][64];
    __shared__ __align__(16) bf16 x1t[FF], x2t[FF];

    const int t   = blockIdx.x;
    const int tid = threadIdx.x;
    const float* g1p = g1 + (size_t)t * FF;
    const float* g2p = g2 + (size_t)t * FF;
    bf16* ylp = Yl + (size_t)t * KCAT;
    bf16* yrp = Yr + (size_t)t * KCAT;

    #pragma unroll
    for (int c = 0; c < 4; ++c) {
        int idx4 = (c * 256 + tid) * 4;
        float4 v1 = *(const float4*)(g1p + idx4);
        float4 v2 = *(const float4*)(g2p + idx4);
        int h = idx4 >> 9, e = idx4 & 511;
        *(float4*)&g1t[h * GPAD + e] = v1;
        *(float4*)&g2t[h * GPAD + e] = v2;
    }
    #pragma unroll
    for (int c = 0; c < 2; ++c) {
        int idx8 = (c * 256 + tid) * 8;
        *(bf16x8*)&x1t[idx8] = *(const bf16x8*)(ylp + idx8);
        *(bf16x8*)&x2t[idx8] = *(const bf16x8*)(yrp + FF + idx8);
    }
    __syncthreads();

    #pragma unroll
    for (int c = 0; c < 2; ++c) {
        int e = c * 256 + tid;
        float s1 = 0.f, s2 = 0.f;
        #pragma unroll
        for (int h = 0; h < 8; ++h) { s1 += g1t[h * GPAD + e]; s2 += g2t[h * GPAD + e]; }
        g1s[e] = s1; g2s[e] = s2;
    }

    {   // t1[h,m] = sum_e x1[e,m]*g1[h,e] ; t2 likewise. 4-way partials.
        int o = tid & 63;
        int h = o & 7, m = o >> 3;
        int p = tid >> 6;
        float s1 = 0.f, s2 = 0.f;
        #pragma unroll 8
        for (int ii = 0; ii < 128; ++ii) {
            int e = p * 128 + ii;
            float xv1 = __bfloat162float(x1t[e * 8 + m]);
            float xv2 = __bfloat162float(x2t[e * 8 + m]);
            s1 += xv1 * g1t[h * GPAD + e];
            s2 += xv2 * g2t[h * GPAD + e];
        }
        t1p[p][o] = s1; t2p[p][o] = s2;
    }
    __syncthreads();
    if (tid < 64)       t1s[tid] = t1p[0][tid] + t1p[1][tid] + t1p[2][tid] + t1p[3][tid];
    else if (tid < 128) { int o = tid - 64; t2s[o] = t2p[0][o] + t2p[1][o] + t2p[2][o] + t2p[3][o]; }
    __syncthreads();

    #pragma unroll
    for (int c = 0; c < 2; ++c) {
        int f0 = (c * 256 + tid) * 8;
        int e  = f0 >> 3;
        float s1 = g1s[e], s2 = g2s[e];
        bf16x8 xa = *(const bf16x8*)&x1t[f0];
        bf16x8 xb = *(const bf16x8*)&x2t[f0];
        bf16x8 o1, o2;
        #pragma unroll
        for (int u = 0; u < 8; ++u) {
            o1[u] = (__bf16)((float)xa[u] * s1);
            o2[u] = (__bf16)((float)xb[u] * s2);
        }
        *(bf16x8*)(ylp + f0)      = o1;
        *(bf16x8*)(yrp + FF + f0) = o2;
    }
    #pragma unroll
    for (int c = 0; c < 2; ++c) {
        int f0 = (c * 256 + tid) * 8;
        int i  = f0 >> 3;
        bf16x8 o12v, o21v;
        #pragma unroll
        for (int m = 0; m < 8; ++m) {
            float s12 = 0.f, s21 = 0.f;
            #pragma unroll
            for (int h = 0; h < 8; ++h) {
                s12 += t2s[(m << 3) | h] * g1t[h * GPAD + i];
                s21 += t1s[(m << 3) | h] * g2t[h * GPAD + i];
            }
            o12v[m] = (__bf16)s12;
            o21v[m] = (__bf16)s21;
        }
        *(bf16x8*)(ylp + FF + f0) = o12v;
        *(bf16x8*)(yrp + f0)      = o21v;
    }
    {
        int e0 = tid * 2;
        ylp[2 * FF + e0]     = __float2bfloat16(g1s[e0]);
        ylp[2 * FF + e0 + 1] = __float2bfloat16(g1s[e0 + 1]);
        yrp[2 * FF + e0]     = __float2bfloat16(g2s[e0]);
        yrp[2 * FF + e0 + 1] = __float2bfloat16(g2s[e0 + 1]);
    }
}

// ---------------- launch ----------------

extern "C" void kernel_launch(void* const* d_in, const int* in_sizes, int n_in,
                              void* d_out, int out_size, void* d_ws, size_t ws_size,
                              hipStream_t stream) {
    const float* x    = (const float*)d_in[0];
    const float* g1   = (const float*)d_in[1];
    const float* g2   = (const float*)d_in[2];
    const float* u1_w = (const float*)d_in[3];
    const float* u1_b = (const float*)d_in[4];
    const float* u2_w = (const float*)d_in[5];
    const float* u2_b = (const float*)d_in[6];
    const float* v11  = (const float*)d_in[7];
    const float* v12  = (const float*)d_in[8];
    const float* v21  = (const float*)d_in[9];
    const float* v22  = (const float*)d_in[10];
    const float* b1   = (const float*)d_in[11];
    const float* b2   = (const float*)d_in[12];
    float* out = (float*)d_out;

    size_t off = 0;
    char* base = (char*)d_ws;
    auto take = [&](size_t bytes) { void* p = base + off; off += (bytes + 255) & ~(size_t)255; return p; };
    bf16* Xb  = (bf16*)take((size_t)TOK * DD * 2);
    bf16* U1b = (bf16*)take((size_t)FF * DD * 2);
    bf16* U2b = (bf16*)take((size_t)FF * DD * 2);
    bf16* Wl  = (bf16*)take((size_t)HALF * KCAT * 2);
    bf16* Wr  = (bf16*)take((size_t)HALF * KCAT * 2);
    bf16* Yl  = (bf16*)take((size_t)TOK * KCAT * 2);
    bf16* Yr  = (bf16*)take((size_t)TOK * KCAT * 2);

    // prep
    cvt_bf16<<<4096, 256, 0, stream>>>(x,    Xb,  TOK * DD / 4);
    cvt_bf16<<<2048, 256, 0, stream>>>(u1_w, U1b, FF * DD / 4);
    cvt_bf16<<<2048, 256, 0, stream>>>(u2_w, U2b, FF * DD / 4);
    pack_w<<<HALF, 256, 0, stream>>>(v11, v12, b1, Wl);
    pack_w<<<HALF, 256, 0, stream>>>(v21, v22, b2, Wr);

    // fused U-GEMMs: x1raw -> Yl[:,0:4096], x2raw -> Yr[:,4096:8192]  (relu^2, bf16)
    gemm32<1><<<2 * (TOK / 256) * (FF / 256), 512, 0, stream>>>(
        Xb, U1b, u1_b, Yl,
        Xb, U2b, u2_b, Yr + FF,
        TOK / 256, FF / 256, DD, KCAT);

    // gating / tiny einsums
    glue<<<TOK, 256, 0, stream>>>(g1, g2, Yl, Yr);

    // fused V-GEMMs: out[:,0:1024] = Yl @ Wl^T ; out[:,1024:2048] = Yr @ Wr^T  (fp32)
    gemm32<0><<<2 * (TOK / 256) * (HALF / 256), 512, 0, stream>>>(
        Yl, Wl, nullptr, out,
        Yr, Wr, nullptr, out + HALF,
        TOK / 256, HALF / 256, KCAT, DD);
}

// Round 4
// 765.711 us; speedup vs baseline: 1.0853x; 1.0853x over previous
//
#include <hip/hip_runtime.h>
#include <hip/hip_bf16.h>

// MonetMoVDE: B=4 T=2048 D=2048 H=8 E=512 M=8, F=4096, HALF=1024
#define TOK   8192   // B*T
#define DD    2048
#define FF    4096
#define EE    512
#define HALF  1024
#define KCAT  8704   // F + F + E  (concat K for V-GEMMs, 8704 = 136*64)

typedef __bf16 bf16x8 __attribute__((ext_vector_type(8)));
typedef __bf16 bf16x4 __attribute__((ext_vector_type(4)));
typedef float  f32x4  __attribute__((ext_vector_type(4)));
typedef float  f32x16 __attribute__((ext_vector_type(16)));
using bf16 = __hip_bfloat16;

#define AS1(p) ((const __attribute__((address_space(1))) void*)(p))
#define AS3(p) ((__attribute__((address_space(3))) void*)(p))

// ---------------- prep kernels ----------------

__global__ void cvt_bf16(const float* __restrict__ in, bf16* __restrict__ out, int n4) {
    int i = blockIdx.x * blockDim.x + threadIdx.x;
    int stride = gridDim.x * blockDim.x;
    for (; i < n4; i += stride) {
        float4 v = ((const float4*)in)[i];
        bf16x4 o;
        o[0] = (__bf16)v.x; o[1] = (__bf16)v.y; o[2] = (__bf16)v.z; o[3] = (__bf16)v.w;
        ((bf16x4*)out)[i] = o;
    }
}

// W [1024][8704] = [vA | vB | bT]   (vA,vB: [1024][4096] f32; bmat: [512][1024] f32)
__global__ void pack_w(const float* __restrict__ vA, const float* __restrict__ vB,
                       const float* __restrict__ bmat, bf16* __restrict__ W) {
    int n = blockIdx.x;
    const float* ra = vA + (size_t)n * FF;
    const float* rb = vB + (size_t)n * FF;
    bf16* w = W + (size_t)n * KCAT;
    for (int k = threadIdx.x; k < FF; k += 256) {
        w[k]      = __float2bfloat16(ra[k]);
        w[FF + k] = __float2bfloat16(rb[k]);
    }
    for (int e = threadIdx.x; e < EE; e += 256)
        w[2 * FF + e] = __float2bfloat16(bmat[(size_t)e * HALF + n]);
}

// ---------------- GEMM: C[m,n] = sum_k A[m,k] * Bw[n,k] ----------------
// 256x256 tile, BK=64, 8 waves (2Mx4N), 32x32x16 bf16 MFMA, per-wave C 128x64.
// LDS per buffer (64KB): A01 @0, A23 @16K, B01 @32K, B23 @48K; sub-tile =
// 256 rows x 32 K-elems (64B rows), XOR swizzle byte ^= (((row>>1)&3)<<4)
// (16-lane read cohort -> 2 lanes per bank start == conflict-free, r2-verified).
// 4 phases per K-tile (kk=0..3); phase q stages sub-tile q of tile t+1 into
// the other buffer; vmcnt(4) at odd-phase ends (counted, never 0 mid-loop).
// Fused dual-GEMM; MODE 0: fp32 store, MODE 1: relu(z+bias)^2 -> bf16 store.
template<int MODE>
__global__ __launch_bounds__(512, 2)
void gemm32(const bf16* __restrict__ A0, const bf16* __restrict__ B0,
            const float* __restrict__ bias0, void* __restrict__ C0,
            const bf16* __restrict__ A1, const bf16* __restrict__ B1,
            const float* __restrict__ bias1, void* __restrict__ C1,
            int nbm, int nbn, int K, int ldc)
{
    __shared__ __align__(16) char smem[131072];   // 2 x 64KB
    const int tid  = threadIdx.x;
    const int lane = tid & 63;
    const int wid  = tid >> 6;
    const int wm = wid >> 2, wn = wid & 3;
    const int ln31 = lane & 31, kb = lane >> 5;

    int bid = blockIdx.x;
    {   // bijective XCD swizzle (m204)
        int nwg = gridDim.x;
        int q = nwg >> 3, r = nwg & 7;
        int xcd = bid & 7, idx = bid >> 3;
        bid = (xcd < r ? xcd * (q + 1) : r * (q + 1) + (xcd - r) * q) + idx;
    }
    const int npg = nbm * nbn;
    const int g   = bid / npg;
    const int lb  = bid - g * npg;
    const int bm = lb / nbn, bn = lb - bm * nbn;

    const bf16*  A    = g ? A1 : A0;
    const bf16*  Bw   = g ? B1 : B0;
    const float* bias = g ? bias1 : bias0;
    char* Cout = (char*)(g ? C1 : C0);

    const long row0 = (long)bm * 256;
    const int  col0 = bn * 256;
    const int  nt   = K >> 6;

    // staging sources (pre-swizzled; involution) + linear LDS dest offsets
    const char* gA[2]; const char* gB[2];
    uint32_t ldst0, ldst1;
    #pragma unroll
    for (int l = 0; l < 2; ++l) {
        const uint32_t S = (uint32_t)(l * 512 + tid) * 16;
        const int r  = (int)(S >> 6);                       // sub-tile row 0..255
        const int cb = (int)((S & 63) ^ ((uint32_t)((r >> 1) & 3) << 4));
        gA[l] = (const char*)A + (row0 + r) * (long)K * 2 + cb;
        gB[l] = (const char*)Bw + (long)(col0 + r) * K * 2 + cb;
    }
    ldst0 = (uint32_t)(tid & ~63) * 16;
    ldst1 = 8192u + (uint32_t)(tid & ~63) * 16;

    // per-lane LDS read offsets (within sub-tile); row = <base>+ln31, swizzle
    // uses ((row>>1)&3) == ((lane>>1)&3) since all row bases are mult. of 64
    const uint32_t aB = (uint32_t)(wm * 128 + ln31) * 64;
    const uint32_t bB = 32768u + (uint32_t)(wn * 64 + ln31) * 64;
    const uint32_t fr = (uint32_t)((lane >> 1) & 3);
    const uint32_t coffE = ((uint32_t)kb ^ fr) << 4;         // even phase (kkL=0)
    const uint32_t coffO = (((uint32_t)kb | 2u) ^ fr) << 4;  // odd phase  (kkL=1)

    f32x16 acc[4][2];
    #pragma unroll
    for (int i = 0; i < 4; ++i)
        #pragma unroll
        for (int j = 0; j < 2; ++j)
            acc[i][j] = (f32x16)(0.f);

    // prologue: stage tile 0 into buf0 (order A01,B01,A23,B23)
    __builtin_amdgcn_global_load_lds(AS1(gA[0]),      AS3(smem +     0 + ldst0), 16, 0, 0);
    __builtin_amdgcn_global_load_lds(AS1(gA[1]),      AS3(smem +     0 + ldst1), 16, 0, 0);
    __builtin_amdgcn_global_load_lds(AS1(gB[0]),      AS3(smem + 32768 + ldst0), 16, 0, 0);
    __builtin_amdgcn_global_load_lds(AS1(gB[1]),      AS3(smem + 32768 + ldst1), 16, 0, 0);
    __builtin_amdgcn_global_load_lds(AS1(gA[0] + 64), AS3(smem + 16384 + ldst0), 16, 0, 0);
    __builtin_amdgcn_global_load_lds(AS1(gA[1] + 64), AS3(smem + 16384 + ldst1), 16, 0, 0);
    __builtin_amdgcn_global_load_lds(AS1(gB[0] + 64), AS3(smem + 49152 + ldst0), 16, 0, 0);
    __builtin_amdgcn_global_load_lds(AS1(gB[1] + 64), AS3(smem + 49152 + ldst1), 16, 0, 0);
    asm volatile("s_waitcnt vmcnt(4)\n\ts_barrier" ::: "memory");

#define MFMA8()                                                                        \
    __builtin_amdgcn_s_setprio(1);                                                     \
    acc[0][0] = __builtin_amdgcn_mfma_f32_32x32x16_bf16(a0, b0, acc[0][0], 0, 0, 0);   \
    acc[0][1] = __builtin_amdgcn_mfma_f32_32x32x16_bf16(a0, b1, acc[0][1], 0, 0, 0);   \
    acc[1][0] = __builtin_amdgcn_mfma_f32_32x32x16_bf16(a1, b0, acc[1][0], 0, 0, 0);   \
    acc[1][1] = __builtin_amdgcn_mfma_f32_32x32x16_bf16(a1, b1, acc[1][1], 0, 0, 0);   \
    acc[2][0] = __builtin_amdgcn_mfma_f32_32x32x16_bf16(a2, b0, acc[2][0], 0, 0, 0);   \
    acc[2][1] = __builtin_amdgcn_mfma_f32_32x32x16_bf16(a2, b1, acc[2][1], 0, 0, 0);   \
    acc[3][0] = __builtin_amdgcn_mfma_f32_32x32x16_bf16(a3, b0, acc[3][0], 0, 0, 0);   \
    acc[3][1] = __builtin_amdgcn_mfma_f32_32x32x16_bf16(a3, b1, acc[3][1], 0, 0, 0);   \
    __builtin_amdgcn_s_setprio(0);

#define PHASE(Q, LOFF, COFFv)                                                          \
    {                                                                                  \
        if (st) {                                                                      \
            __builtin_amdgcn_global_load_lds(                                          \
                AS1(((Q & 1) ? gB : gA)[0] + koff + (Q >> 1) * 64),                    \
                AS3(pt + LOFF + ldst0), 16, 0, 0);                                     \
            __builtin_amdgcn_global_load_lds(                                          \
                AS1(((Q & 1) ? gB : gA)[1] + koff + (Q >> 1) * 64),                    \
                AS3(pt + LOFF + ldst1), 16, 0, 0);                                     \
        }                                                                              \
        const char* ps = pb + (Q >> 1) * 16384;                                        \
        bf16x8 a0 = *(const bf16x8*)(ps + aB + COFFv);                                 \
        bf16x8 a1 = *(const bf16x8*)(ps + aB + 2048 + COFFv);                          \
        bf16x8 a2 = *(const bf16x8*)(ps + aB + 4096 + COFFv);                          \
        bf16x8 a3 = *(const bf16x8*)(ps + aB + 6144 + COFFv);                          \
        bf16x8 b0 = *(const bf16x8*)(ps + bB + COFFv);                                 \
        bf16x8 b1 = *(const bf16x8*)(ps + bB + 2048 + COFFv);                          \
        asm volatile("s_barrier" ::: "memory");                                        \
        MFMA8();                                                                       \
    }

    for (int t = 0; t < nt; ++t) {
        char* pb = smem + (t & 1) * 65536;
        char* pt = smem + ((t + 1) & 1) * 65536;
        const bool st = (t + 1 < nt);
        const long koff = (long)(t + 1) * 128;

        PHASE(0, 0, coffE)
        asm volatile("s_barrier" ::: "memory");
        PHASE(1, 32768, coffO)
        if (st) asm volatile("s_waitcnt vmcnt(4)" ::: "memory");
        else    asm volatile("s_waitcnt vmcnt(0)" ::: "memory");
        asm volatile("s_barrier" ::: "memory");
        PHASE(2, 16384, coffE)
        asm volatile("s_barrier" ::: "memory");
        PHASE(3, 49152, coffO)
        if (st) asm volatile("s_waitcnt vmcnt(4)" ::: "memory");
        asm volatile("s_barrier" ::: "memory");
    }
#undef PHASE
#undef MFMA8

    // epilogue: 32x32 C/D layout: col = ln31, row = (rg&3) + 8*(rg>>2) + 4*kb
    const int rowb = wm * 128 + kb * 4;
    const int colb = col0 + wn * 64 + ln31;
    #pragma unroll
    for (int i = 0; i < 4; ++i) {
        #pragma unroll
        for (int j = 0; j < 2; ++j) {
            const int cc = colb + j * 32;
            float badd = 0.f;
            if (MODE == 1) badd = bias[cc];
            #pragma unroll
            for (int rg = 0; rg < 16; ++rg) {
                long row = row0 + rowb + i * 32 + (rg & 3) + 8 * (rg >> 2);
                float v = acc[i][j][rg];
                if (MODE == 1) {
                    v += badd;
                    v = fmaxf(v, 0.f);
                    v = v * v;
                    ((bf16*)Cout)[row * ldc + cc] = __float2bfloat16(v);
                } else {
                    ((float*)Cout)[row * ldc + cc] = v;
                }
            }
        }
    }
}

// ---------------- glue: per-token gating / tiny einsums ----------------
// In:  g1,g2 [TOK][8][512] f32; Yl[:,0:4096]=x1 raw bf16; Yr[:,4096:8192]=x2 raw bf16
// Out: Yl = [x1*g1s | y12 | g1s]; Yr = [y21 | x2*g2s | g2s]  (all bf16)
#define GPAD 524   // 8-row pad: h-stride hits 8 distinct banks; 524*4%16==0
__global__ __launch_bounds__(256)
void glue(const float* __restrict__ g1, const float* __restrict__ g2,
          bf16* __restrict__ Yl, bf16* __restrict__ Yr)
{
    __shared__ __align__(16) float g1t[8 * GPAD];
    __shared__ __align__(16) float g2t[8 * GPAD];
    __shared__ float g1s[EE], g2s[EE];
    __shared__ float t1s[64], t2s[64];
    __shared__ float t1p[4][64], t2p[4][64];
    __shared__ __align__(16) bf16 x1t[FF], x2t[FF];

    const int t   = blockIdx.x;
    const int tid = threadIdx.x;
    const float* g1p = g1 + (size_t)t * FF;
    const float* g2p = g2 + (size_t)t * FF;
    bf16* ylp = Yl + (size_t)t * KCAT;
    bf16* yrp = Yr + (size_t)t * KCAT;

    #pragma unroll
    for (int c = 0; c < 4; ++c) {
        int idx4 = (c * 256 + tid) * 4;
        float4 v1 = *(const float4*)(g1p + idx4);
        float4 v2 = *(const float4*)(g2p + idx4);
        int h = idx4 >> 9, e = idx4 & 511;
        *(float4*)&g1t[h * GPAD + e] = v1;
        *(float4*)&g2t[h * GPAD + e] = v2;
    }
    #pragma unroll
    for (int c = 0; c < 2; ++c) {
        int idx8 = (c * 256 + tid) * 8;
        *(bf16x8*)&x1t[idx8] = *(const bf16x8*)(ylp + idx8);
        *(bf16x8*)&x2t[idx8] = *(const bf16x8*)(yrp + FF + idx8);
    }
    __syncthreads();

    #pragma unroll
    for (int c = 0; c < 2; ++c) {
        int e = c * 256 + tid;
        float s1 = 0.f, s2 = 0.f;
        #pragma unroll
        for (int h = 0; h < 8; ++h) { s1 += g1t[h * GPAD + e]; s2 += g2t[h * GPAD + e]; }
        g1s[e] = s1; g2s[e] = s2;
    }

    {   // t1[h,m] = sum_e x1[e,m]*g1[h,e] ; t2 likewise. 4-way partials.
        int o = tid & 63;
        int h = o & 7, m = o >> 3;
        int p = tid >> 6;
        float s1 = 0.f, s2 = 0.f;
        #pragma unroll 8
        for (int ii = 0; ii < 128; ++ii) {
            int e = p * 128 + ii;
            float xv1 = __bfloat162float(x1t[e * 8 + m]);
            float xv2 = __bfloat162float(x2t[e * 8 + m]);
            s1 += xv1 * g1t[h * GPAD + e];
            s2 += xv2 * g2t[h * GPAD + e];
        }
        t1p[p][o] = s1; t2p[p][o] = s2;
    }
    __syncthreads();
    if (tid < 64)       t1s[tid] = t1p[0][tid] + t1p[1][tid] + t1p[2][tid] + t1p[3][tid];
    else if (tid < 128) { int o = tid - 64; t2s[o] = t2p[0][o] + t2p[1][o] + t2p[2][o] + t2p[3][o]; }
    __syncthreads();

    #pragma unroll
    for (int c = 0; c < 2; ++c) {
        int f0 = (c * 256 + tid) * 8;
        int e  = f0 >> 3;
        float s1 = g1s[e], s2 = g2s[e];
        bf16x8 xa = *(const bf16x8*)&x1t[f0];
        bf16x8 xb = *(const bf16x8*)&x2t[f0];
        bf16x8 o1, o2;
        #pragma unroll
        for (int u = 0; u < 8; ++u) {
            o1[u] = (__bf16)((float)xa[u] * s1);
            o2[u] = (__bf16)((float)xb[u] * s2);
        }
        *(bf16x8*)(ylp + f0)      = o1;
        *(bf16x8*)(yrp + FF + f0) = o2;
    }
    #pragma unroll
    for (int c = 0; c < 2; ++c) {
        int f0 = (c * 256 + tid) * 8;
        int i  = f0 >> 3;
        bf16x8 o12v, o21v;
        #pragma unroll
        for (int m = 0; m < 8; ++m) {
            float s12 = 0.f, s21 = 0.f;
            #pragma unroll
            for (int h = 0; h < 8; ++h) {
                s12 += t2s[(m << 3) | h] * g1t[h * GPAD + i];
                s21 += t1s[(m << 3) | h] * g2t[h * GPAD + i];
            }
            o12v[m] = (__bf16)s12;
            o21v[m] = (__bf16)s21;
        }
        *(bf16x8*)(ylp + FF + f0) = o12v;
        *(bf16x8*)(yrp + f0)      = o21v;
    }
    {
        int e0 = tid * 2;
        ylp[2 * FF + e0]     = __float2bfloat16(g1s[e0]);
        ylp[2 * FF + e0 + 1] = __float2bfloat16(g1s[e0 + 1]);
        yrp[2 * FF + e0]     = __float2bfloat16(g2s[e0]);
        yrp[2 * FF + e0 + 1] = __float2bfloat16(g2s[e0 + 1]);
    }
}

// ---------------- launch ----------------

extern "C" void kernel_launch(void* const* d_in, const int* in_sizes, int n_in,
                              void* d_out, int out_size, void* d_ws, size_t ws_size,
                              hipStream_t stream) {
    const float* x    = (const float*)d_in[0];
    const float* g1   = (const float*)d_in[1];
    const float* g2   = (const float*)d_in[2];
    const float* u1_w = (const float*)d_in[3];
    const float* u1_b = (const float*)d_in[4];
    const float* u2_w = (const float*)d_in[5];
    const float* u2_b = (const float*)d_in[6];
    const float* v11  = (const float*)d_in[7];
    const float* v12  = (const float*)d_in[8];
    const float* v21  = (const float*)d_in[9];
    const float* v22  = (const float*)d_in[10];
    const float* b1   = (const float*)d_in[11];
    const float* b2   = (const float*)d_in[12];
    float* out = (float*)d_out;

    size_t off = 0;
    char* base = (char*)d_ws;
    auto take = [&](size_t bytes) { void* p = base + off; off += (bytes + 255) & ~(size_t)255; return p; };
    bf16* Xb  = (bf16*)take((size_t)TOK * DD * 2);
    bf16* U1b = (bf16*)take((size_t)FF * DD * 2);
    bf16* U2b = (bf16*)take((size_t)FF * DD * 2);
    bf16* Wl  = (bf16*)take((size_t)HALF * KCAT * 2);
    bf16* Wr  = (bf16*)take((size_t)HALF * KCAT * 2);
    bf16* Yl  = (bf16*)take((size_t)TOK * KCAT * 2);
    bf16* Yr  = (bf16*)take((size_t)TOK * KCAT * 2);

    // prep
    cvt_bf16<<<4096, 256, 0, stream>>>(x,    Xb,  TOK * DD / 4);
    cvt_bf16<<<2048, 256, 0, stream>>>(u1_w, U1b, FF * DD / 4);
    cvt_bf16<<<2048, 256, 0, stream>>>(u2_w, U2b, FF * DD / 4);
    pack_w<<<HALF, 256, 0, stream>>>(v11, v12, b1, Wl);
    pack_w<<<HALF, 256, 0, stream>>>(v21, v22, b2, Wr);

    // fused U-GEMMs: x1raw -> Yl[:,0:4096], x2raw -> Yr[:,4096:8192]  (relu^2, bf16)
    gemm32<1><<<2 * (TOK / 256) * (FF / 256), 512, 0, stream>>>(
        Xb, U1b, u1_b, Yl,
        Xb, U2b, u2_b, Yr + FF,
        TOK / 256, FF / 256, DD, KCAT);

    // gating / tiny einsums
    glue<<<TOK, 256, 0, stream>>>(g1, g2, Yl, Yr);

    // fused V-GEMMs: out[:,0:1024] = Yl @ Wl^T ; out[:,1024:2048] = Yr @ Wr^T  (fp32)
    gemm32<0><<<2 * (TOK / 256) * (HALF / 256), 512, 0, stream>>>(
        Yl, Wl, nullptr, out,
        Yr, Wr, nullptr, out + HALF,
        TOK / 256, HALF / 256, KCAT, DD);
}

// Round 5
// 714.355 us; speedup vs baseline: 1.1633x; 1.0719x over previous
//
#include <hip/hip_runtime.h>
#include <hip/hip_bf16.h>

// MonetMoVDE: B=4 T=2048 D=2048 H=8 E=512 M=8, F=4096, HALF=1024
#define TOK   8192   // B*T
#define DD    2048
#define FF    4096
#define EE    512
#define HALF  1024
#define KCAT  8704   // F + F + E  (concat K for V-GEMMs, 8704 = 136*64)

typedef __bf16 bf16x8 __attribute__((ext_vector_type(8)));
typedef __bf16 bf16x4 __attribute__((ext_vector_type(4)));
typedef float  f32x4  __attribute__((ext_vector_type(4)));
using bf16 = __hip_bfloat16;

#define AS1(p) ((const __attribute__((address_space(1))) void*)(p))
#define AS3(p) ((__attribute__((address_space(3))) void*)(p))

// ---------------- prep kernels ----------------

__global__ void cvt_bf16(const float* __restrict__ in, bf16* __restrict__ out, int n4) {
    int i = blockIdx.x * blockDim.x + threadIdx.x;
    int stride = gridDim.x * blockDim.x;
    for (; i < n4; i += stride) {
        float4 v = ((const float4*)in)[i];
        bf16x4 o;
        o[0] = (__bf16)v.x; o[1] = (__bf16)v.y; o[2] = (__bf16)v.z; o[3] = (__bf16)v.w;
        ((bf16x4*)out)[i] = o;
    }
}

// W [1024][8704] = [vA | vB | bT]   (vA,vB: [1024][4096] f32; bmat: [512][1024] f32)
__global__ void pack_w(const float* __restrict__ vA, const float* __restrict__ vB,
                       const float* __restrict__ bmat, bf16* __restrict__ W) {
    int n = blockIdx.x;
    const float* ra = vA + (size_t)n * FF;
    const float* rb = vB + (size_t)n * FF;
    bf16* w = W + (size_t)n * KCAT;
    for (int k = threadIdx.x; k < FF; k += 256) {
        w[k]      = __float2bfloat16(ra[k]);
        w[FF + k] = __float2bfloat16(rb[k]);
    }
    for (int e = threadIdx.x; e < EE; e += 256)
        w[2 * FF + e] = __float2bfloat16(bmat[(size_t)e * HALF + n]);
}

// ---------------- GEMM: C[m,n] = sum_k A[m,k] * Bw[n,k] ----------------
// 256x256 tile, BK=64, 8 waves (2Mx4N), 16x16x32 bf16 MFMA, per-wave C 128x64.
// LDS buffer (64KB) = 4 planes of 16KB: A_k0 @0, A_k1 @16K, B_k0 @32K, B_k1 @48K.
// Plane layout = round-2's PROVEN ZERO-CONFLICT scheme: 256 rows x 64B (32 K-elems),
// byte ^= (((row>>1)&3)<<4); reads with r16=lane&15, kb=lane>>4.
// 4 phases per K-tile: (kk,ih) in {(0,0),(0,1),(1,0),(1,1)}; 16 MFMA each;
// B-frags read once per kk, reused across both ih phases (-25% LDS reads).
// Phase q stages plane q of tile t+1 into the other buffer; vmcnt(4) at the
// end of phases 1 and 3 (counted, never 0 mid-loop).
// Fused dual-GEMM; MODE 0: fp32 store, MODE 1: relu(z+bias)^2 -> bf16 store.
template<int MODE>
__global__ __launch_bounds__(512, 2)
void gemmP(const bf16* __restrict__ A0, const bf16* __restrict__ B0,
           const float* __restrict__ bias0, void* __restrict__ C0,
           const bf16* __restrict__ A1, const bf16* __restrict__ B1,
           const float* __restrict__ bias1, void* __restrict__ C1,
           int nbm, int nbn, int K, int ldc)
{
    __shared__ __align__(16) char smem[131072];   // 2 x 64KB
    const int tid  = threadIdx.x;
    const int lane = tid & 63;
    const int wid  = tid >> 6;
    const int wm = wid >> 2, wn = wid & 3;
    const int r16 = lane & 15, kb = lane >> 4;

    int bid = blockIdx.x;
    {   // bijective XCD swizzle (m204)
        int nwg = gridDim.x;
        int q = nwg >> 3, r = nwg & 7;
        int xcd = bid & 7, idx = bid >> 3;
        bid = (xcd < r ? xcd * (q + 1) : r * (q + 1) + (xcd - r) * q) + idx;
    }
    const int npg = nbm * nbn;
    const int g   = bid / npg;
    const int lb  = bid - g * npg;
    const int bm = lb / nbn, bn = lb - bm * nbn;

    const bf16*  A    = g ? A1 : A0;
    const bf16*  Bw   = g ? B1 : B0;
    const float* bias = g ? bias1 : bias0;
    char* Cout = (char*)(g ? C1 : C0);

    const long row0 = (long)bm * 256;
    const int  col0 = bn * 256;
    const int  nt   = K >> 6;

    // staging sources (pre-swizzled; involution) + linear LDS dest offset
    const char* gA[2]; const char* gB[2];
    #pragma unroll
    for (int l = 0; l < 2; ++l) {
        const uint32_t S = (uint32_t)(l * 512 + tid) * 16;   // byte slot in 16KB plane
        const int r  = (int)(S >> 6);                        // plane row 0..255
        const int cb = (int)((S & 63) ^ ((uint32_t)((r >> 1) & 3) << 4));
        gA[l] = (const char*)A  + (row0 + r) * (long)K * 2 + cb;
        gB[l] = (const char*)Bw + (long)(col0 + r) * K * 2 + cb;
    }
    const uint32_t ldst = (uint32_t)(tid & ~63) * 16;        // + l*8192 + plane base

    // per-lane read base offsets within a plane (swizzled; round-2 exact)
    const uint32_t swz  = ((uint32_t)(r16 >> 1) & 3u) << 4;
    const uint32_t aoff = (uint32_t)((wm * 128 + r16) * 64 + kb * 16) ^ swz;  // +ih*4096 +fi*1024
    const uint32_t boff = (uint32_t)((wn * 64  + r16) * 64 + kb * 16) ^ swz;  // +fj*1024

    f32x4 acc[8][4];
    #pragma unroll
    for (int i = 0; i < 8; ++i)
        #pragma unroll
        for (int j = 0; j < 4; ++j)
            acc[i][j] = (f32x4){0.f, 0.f, 0.f, 0.f};

    // prologue: stage all 4 planes of tile 0 into buf0
    __builtin_amdgcn_global_load_lds(AS1(gA[0]),      AS3(smem +     0 + ldst), 16, 0, 0);
    __builtin_amdgcn_global_load_lds(AS1(gA[1]),      AS3(smem +  8192 + ldst), 16, 0, 0);
    __builtin_amdgcn_global_load_lds(AS1(gB[0]),      AS3(smem + 32768 + ldst), 16, 0, 0);
    __builtin_amdgcn_global_load_lds(AS1(gB[1]),      AS3(smem + 40960 + ldst), 16, 0, 0);
    __builtin_amdgcn_global_load_lds(AS1(gA[0] + 64), AS3(smem + 16384 + ldst), 16, 0, 0);
    __builtin_amdgcn_global_load_lds(AS1(gA[1] + 64), AS3(smem + 24576 + ldst), 16, 0, 0);
    __builtin_amdgcn_global_load_lds(AS1(gB[0] + 64), AS3(smem + 49152 + ldst), 16, 0, 0);
    __builtin_amdgcn_global_load_lds(AS1(gB[1] + 64), AS3(smem + 57344 + ldst), 16, 0, 0);
    asm volatile("s_waitcnt vmcnt(4)\n\ts_barrier" ::: "memory");

#define MFMA16(IH)                                                                       \
    __builtin_amdgcn_s_setprio(1);                                                      \
    _Pragma("unroll")                                                                    \
    for (int fi = 0; fi < 4; ++fi) {                                                     \
        acc[(IH)*4+fi][0] = __builtin_amdgcn_mfma_f32_16x16x32_bf16(af[fi], bv[0], acc[(IH)*4+fi][0], 0, 0, 0); \
        acc[(IH)*4+fi][1] = __builtin_amdgcn_mfma_f32_16x16x32_bf16(af[fi], bv[1], acc[(IH)*4+fi][1], 0, 0, 0); \
        acc[(IH)*4+fi][2] = __builtin_amdgcn_mfma_f32_16x16x32_bf16(af[fi], bv[2], acc[(IH)*4+fi][2], 0, 0, 0); \
        acc[(IH)*4+fi][3] = __builtin_amdgcn_mfma_f32_16x16x32_bf16(af[fi], bv[3], acc[(IH)*4+fi][3], 0, 0, 0); \
    }                                                                                    \
    __builtin_amdgcn_s_setprio(0);

    for (int t = 0; t < nt; ++t) {
        const char* pb = smem + (t & 1) * 65536;
        char*       pt = smem + ((t + 1) & 1) * 65536;
        const bool  st = (t + 1 < nt);
        const long  koff = (long)(t + 1) * 128;

        bf16x8 af[4], bv[4];

        // ---- phase 0: kk=0, ih=0 ----
        #pragma unroll
        for (int fj = 0; fj < 4; ++fj) bv[fj] = *(const bf16x8*)(pb + 32768 + boff + fj * 1024);
        #pragma unroll
        for (int fi = 0; fi < 4; ++fi) af[fi] = *(const bf16x8*)(pb + aoff + fi * 1024);
        if (st) {
            __builtin_amdgcn_global_load_lds(AS1(gA[0] + koff), AS3(pt +    0 + ldst), 16, 0, 0);
            __builtin_amdgcn_global_load_lds(AS1(gA[1] + koff), AS3(pt + 8192 + ldst), 16, 0, 0);
        }
        asm volatile("s_barrier" ::: "memory");
        MFMA16(0)
        asm volatile("s_barrier" ::: "memory");

        // ---- phase 1: kk=0, ih=1 (reuse bv) ----
        #pragma unroll
        for (int fi = 0; fi < 4; ++fi) af[fi] = *(const bf16x8*)(pb + 4096 + aoff + fi * 1024);
        if (st) {
            __builtin_amdgcn_global_load_lds(AS1(gB[0] + koff), AS3(pt + 32768 + ldst), 16, 0, 0);
            __builtin_amdgcn_global_load_lds(AS1(gB[1] + koff), AS3(pt + 40960 + ldst), 16, 0, 0);
            asm volatile("s_waitcnt vmcnt(4)" ::: "memory");
        } else {
            asm volatile("s_waitcnt vmcnt(0)" ::: "memory");
        }
        asm volatile("s_barrier" ::: "memory");
        MFMA16(1)
        asm volatile("s_barrier" ::: "memory");

        // ---- phase 2: kk=1, ih=0 ----
        #pragma unroll
        for (int fj = 0; fj < 4; ++fj) bv[fj] = *(const bf16x8*)(pb + 49152 + boff + fj * 1024);
        #pragma unroll
        for (int fi = 0; fi < 4; ++fi) af[fi] = *(const bf16x8*)(pb + 16384 + aoff + fi * 1024);
        if (st) {
            __builtin_amdgcn_global_load_lds(AS1(gA[0] + koff + 64), AS3(pt + 16384 + ldst), 16, 0, 0);
            __builtin_amdgcn_global_load_lds(AS1(gA[1] + koff + 64), AS3(pt + 24576 + ldst), 16, 0, 0);
        }
        asm volatile("s_barrier" ::: "memory");
        MFMA16(0)
        asm volatile("s_barrier" ::: "memory");

        // ---- phase 3: kk=1, ih=1 (reuse bv) ----
        #pragma unroll
        for (int fi = 0; fi < 4; ++fi) af[fi] = *(const bf16x8*)(pb + 16384 + 4096 + aoff + fi * 1024);
        if (st) {
            __builtin_amdgcn_global_load_lds(AS1(gB[0] + koff + 64), AS3(pt + 49152 + ldst), 16, 0, 0);
            __builtin_amdgcn_global_load_lds(AS1(gB[1] + koff + 64), AS3(pt + 57344 + ldst), 16, 0, 0);
            asm volatile("s_waitcnt vmcnt(4)" ::: "memory");
        }
        asm volatile("s_barrier" ::: "memory");
        MFMA16(1)
        asm volatile("s_barrier" ::: "memory");
    }
#undef MFMA16

    // epilogue: row = row0 + wm*128 + i*16 + (lane>>4)*4 + e ; col = col0 + wn*64 + j*16 + r16
    const int rb = (lane >> 4) * 4;
    #pragma unroll
    for (int i = 0; i < 8; ++i) {
        #pragma unroll
        for (int j = 0; j < 4; ++j) {
            const int cc = col0 + wn * 64 + j * 16 + r16;
            float badd = 0.f;
            if (MODE == 1) badd = bias[cc];
            #pragma unroll
            for (int e = 0; e < 4; ++e) {
                long row = row0 + wm * 128 + i * 16 + rb + e;
                float v = acc[i][j][e];
                if (MODE == 1) {
                    v += badd;
                    v = fmaxf(v, 0.f);
                    v = v * v;
                    ((bf16*)Cout)[row * ldc + cc] = __float2bfloat16(v);
                } else {
                    ((float*)Cout)[row * ldc + cc] = v;
                }
            }
        }
    }
}

// ---------------- glue: per-token gating / tiny einsums ----------------
// In:  g1,g2 [TOK][8][512] f32; Yl[:,0:4096]=x1 raw bf16; Yr[:,4096:8192]=x2 raw bf16
// Out: Yl = [x1*g1s | y12 | g1s]; Yr = [y21 | x2*g2s | g2s]  (all bf16)
#define GPAD 524   // 8-row pad: h-stride hits 8 distinct banks; 524*4%16==0
__global__ __launch_bounds__(256)
void glue(const float* __restrict__ g1, const float* __restrict__ g2,
          bf16* __restrict__ Yl, bf16* __restrict__ Yr)
{
    __shared__ __align__(16) float g1t[8 * GPAD];
    __shared__ __align__(16) float g2t[8 * GPAD];
    __shared__ float g1s[EE], g2s[EE];
    __shared__ float t1s[64], t2s[64];
    __shared__ float t1p[4][64], t2p[4][64];
    __shared__ __align__(16) bf16 x1t[FF], x2t[FF];

    const int t   = blockIdx.x;
    const int tid = threadIdx.x;
    const float* g1p = g1 + (size_t)t * FF;
    const float* g2p = g2 + (size_t)t * FF;
    bf16* ylp = Yl + (size_t)t * KCAT;
    bf16* yrp = Yr + (size_t)t * KCAT;

    #pragma unroll
    for (int c = 0; c < 4; ++c) {
        int idx4 = (c * 256 + tid) * 4;
        float4 v1 = *(const float4*)(g1p + idx4);
        float4 v2 = *(const float4*)(g2p + idx4);
        int h = idx4 >> 9, e = idx4 & 511;
        *(float4*)&g1t[h * GPAD + e] = v1;
        *(float4*)&g2t[h * GPAD + e] = v2;
    }
    #pragma unroll
    for (int c = 0; c < 2; ++c) {
        int idx8 = (c * 256 + tid) * 8;
        *(bf16x8*)&x1t[idx8] = *(const bf16x8*)(ylp + idx8);
        *(bf16x8*)&x2t[idx8] = *(const bf16x8*)(yrp + FF + idx8);
    }
    __syncthreads();

    #pragma unroll
    for (int c = 0; c < 2; ++c) {
        int e = c * 256 + tid;
        float s1 = 0.f, s2 = 0.f;
        #pragma unroll
        for (int h = 0; h < 8; ++h) { s1 += g1t[h * GPAD + e]; s2 += g2t[h * GPAD + e]; }
        g1s[e] = s1; g2s[e] = s2;
    }

    {   // t1[h,m] = sum_e x1[e,m]*g1[h,e] ; t2 likewise. 4-way partials.
        int o = tid & 63;
        int h = o & 7, m = o >> 3;
        int p = tid >> 6;
        float s1 = 0.f, s2 = 0.f;
        #pragma unroll 8
        for (int ii = 0; ii < 128; ++ii) {
            int e = p * 128 + ii;
            float xv1 = __bfloat162float(x1t[e * 8 + m]);
            float xv2 = __bfloat162float(x2t[e * 8 + m]);
            s1 += xv1 * g1t[h * GPAD + e];
            s2 += xv2 * g2t[h * GPAD + e];
        }
        t1p[p][o] = s1; t2p[p][o] = s2;
    }
    __syncthreads();
    if (tid < 64)       t1s[tid] = t1p[0][tid] + t1p[1][tid] + t1p[2][tid] + t1p[3][tid];
    else if (tid < 128) { int o = tid - 64; t2s[o] = t2p[0][o] + t2p[1][o] + t2p[2][o] + t2p[3][o]; }
    __syncthreads();

    #pragma unroll
    for (int c = 0; c < 2; ++c) {
        int f0 = (c * 256 + tid) * 8;
        int e  = f0 >> 3;
        float s1 = g1s[e], s2 = g2s[e];
        bf16x8 xa = *(const bf16x8*)&x1t[f0];
        bf16x8 xb = *(const bf16x8*)&x2t[f0];
        bf16x8 o1, o2;
        #pragma unroll
        for (int u = 0; u < 8; ++u) {
            o1[u] = (__bf16)((float)xa[u] * s1);
            o2[u] = (__bf16)((float)xb[u] * s2);
        }
        *(bf16x8*)(ylp + f0)      = o1;
        *(bf16x8*)(yrp + FF + f0) = o2;
    }
    #pragma unroll
    for (int c = 0; c < 2; ++c) {
        int f0 = (c * 256 + tid) * 8;
        int i  = f0 >> 3;
        bf16x8 o12v, o21v;
        #pragma unroll
        for (int m = 0; m < 8; ++m) {
            float s12 = 0.f, s21 = 0.f;
            #pragma unroll
            for (int h = 0; h < 8; ++h) {
                s12 += t2s[(m << 3) | h] * g1t[h * GPAD + i];
                s21 += t1s[(m << 3) | h] * g2t[h * GPAD + i];
            }
            o12v[m] = (__bf16)s12;
            o21v[m] = (__bf16)s21;
        }
        *(bf16x8*)(ylp + FF + f0) = o12v;
        *(bf16x8*)(yrp + f0)      = o21v;
    }
    {
        int e0 = tid * 2;
        ylp[2 * FF + e0]     = __float2bfloat16(g1s[e0]);
        ylp[2 * FF + e0 + 1] = __float2bfloat16(g1s[e0 + 1]);
        yrp[2 * FF + e0]     = __float2bfloat16(g2s[e0]);
        yrp[2 * FF + e0 + 1] = __float2bfloat16(g2s[e0 + 1]);
    }
}

// ---------------- launch ----------------

extern "C" void kernel_launch(void* const* d_in, const int* in_sizes, int n_in,
                              void* d_out, int out_size, void* d_ws, size_t ws_size,
                              hipStream_t stream) {
    const float* x    = (const float*)d_in[0];
    const float* g1   = (const float*)d_in[1];
    const float* g2   = (const float*)d_in[2];
    const float* u1_w = (const float*)d_in[3];
    const float* u1_b = (const float*)d_in[4];
    const float* u2_w = (const float*)d_in[5];
    const float* u2_b = (const float*)d_in[6];
    const float* v11  = (const float*)d_in[7];
    const float* v12  = (const float*)d_in[8];
    const float* v21  = (const float*)d_in[9];
    const float* v22  = (const float*)d_in[10];
    const float* b1   = (const float*)d_in[11];
    const float* b2   = (const float*)d_in[12];
    float* out = (float*)d_out;

    size_t off = 0;
    char* base = (char*)d_ws;
    auto take = [&](size_t bytes) { void* p = base + off; off += (bytes + 255) & ~(size_t)255; return p; };
    bf16* Xb  = (bf16*)take((size_t)TOK * DD * 2);
    bf16* U1b = (bf16*)take((size_t)FF * DD * 2);
    bf16* U2b = (bf16*)take((size_t)FF * DD * 2);
    bf16* Wl  = (bf16*)take((size_t)HALF * KCAT * 2);
    bf16* Wr  = (bf16*)take((size_t)HALF * KCAT * 2);
    bf16* Yl  = (bf16*)take((size_t)TOK * KCAT * 2);
    bf16* Yr  = (bf16*)take((size_t)TOK * KCAT * 2);

    // prep
    cvt_bf16<<<4096, 256, 0, stream>>>(x,    Xb,  TOK * DD / 4);
    cvt_bf16<<<2048, 256, 0, stream>>>(u1_w, U1b, FF * DD / 4);
    cvt_bf16<<<2048, 256, 0, stream>>>(u2_w, U2b, FF * DD / 4);
    pack_w<<<HALF, 256, 0, stream>>>(v11, v12, b1, Wl);
    pack_w<<<HALF, 256, 0, stream>>>(v21, v22, b2, Wr);

    // fused U-GEMMs: x1raw -> Yl[:,0:4096], x2raw -> Yr[:,4096:8192]  (relu^2, bf16)
    gemmP<1><<<2 * (TOK / 256) * (FF / 256), 512, 0, stream>>>(
        Xb, U1b, u1_b, Yl,
        Xb, U2b, u2_b, Yr + FF,
        TOK / 256, FF / 256, DD, KCAT);

    // gating / tiny einsums
    glue<<<TOK, 256, 0, stream>>>(g1, g2, Yl, Yr);

    // fused V-GEMMs: out[:,0:1024] = Yl @ Wl^T ; out[:,1024:2048] = Yr @ Wr^T  (fp32)
    gemmP<0><<<2 * (TOK / 256) * (HALF / 256), 512, 0, stream>>>(
        Yl, Wl, nullptr, out,
        Yr, Wr, nullptr, out + HALF,
        TOK / 256, HALF / 256, KCAT, DD);
}

// Round 6
// 692.920 us; speedup vs baseline: 1.1993x; 1.0309x over previous
//
#include <hip/hip_runtime.h>
#include <hip/hip_bf16.h>

// MonetMoVDE: B=4 T=2048 D=2048 H=8 E=512 M=8, F=4096, HALF=1024
#define TOK   8192   // B*T
#define DD    2048
#define FF    4096
#define EE    512
#define HALF  1024
#define KCAT  8704   // F + F + E  (concat K for V-GEMMs, 8704 = 136*64)

typedef __bf16 bf16x8 __attribute__((ext_vector_type(8)));
typedef __bf16 bf16x4 __attribute__((ext_vector_type(4)));
typedef float  f32x4  __attribute__((ext_vector_type(4)));
using bf16 = __hip_bfloat16;

#define AS1(p) ((const __attribute__((address_space(1))) void*)(p))
#define AS3(p) ((__attribute__((address_space(3))) void*)(p))

// ---------------- prep kernels ----------------

__global__ void cvt_bf16(const float* __restrict__ in, bf16* __restrict__ out, int n4) {
    int i = blockIdx.x * blockDim.x + threadIdx.x;
    int stride = gridDim.x * blockDim.x;
    for (; i < n4; i += stride) {
        float4 v = ((const float4*)in)[i];
        bf16x4 o;
        o[0] = (__bf16)v.x; o[1] = (__bf16)v.y; o[2] = (__bf16)v.z; o[3] = (__bf16)v.w;
        ((bf16x4*)out)[i] = o;
    }
}

// W [1024][8704] = [vA | vB | bT]   (vA,vB: [1024][4096] f32; bmat: [512][1024] f32)
__global__ void pack_w(const float* __restrict__ vA, const float* __restrict__ vB,
                       const float* __restrict__ bmat, bf16* __restrict__ W) {
    int n = blockIdx.x;
    const float* ra = vA + (size_t)n * FF;
    const float* rb = vB + (size_t)n * FF;
    bf16* w = W + (size_t)n * KCAT;
    for (int k = threadIdx.x; k < FF; k += 256) {
        w[k]      = __float2bfloat16(ra[k]);
        w[FF + k] = __float2bfloat16(rb[k]);
    }
    for (int e = threadIdx.x; e < EE; e += 256)
        w[2 * FF + e] = __float2bfloat16(bmat[(size_t)e * HALF + n]);
}

// ---------------- GEMM: C[m,n] = sum_k A[m,k] * Bw[n,k] ----------------
// 256x256 tile, BK=64, 8 waves (2Mx4N), 16x16x32 bf16 MFMA, per-wave C 128x64.
// LDS buffer (64KB) = 4 planes of 16KB: A_k0 @0, A_k1 @16K, B_k0 @32K, B_k1 @48K.
// Plane layout = proven zero-conflict scheme (r2/r5): 256 rows x 64B,
// byte ^= (((row>>1)&3)<<4); reads with r16=lane&15, kb=lane>>4.
// REGISTER-PIPELINED phases: each phase {stage 2 gloads; [vmcnt]; barrier;
// ds_read NEXT phase's frags; MFMA on frags read LAST phase}. One barrier
// per phase (4/K-tile); vmcnt(4) counted at ph1/ph3, never 0 mid-loop.
// Fused dual-GEMM; MODE 0: fp32 store, MODE 1: relu(z+bias)^2 -> bf16 store.
template<int MODE>
__global__ __launch_bounds__(512, 2)
void gemmP(const bf16* __restrict__ A0, const bf16* __restrict__ B0,
           const float* __restrict__ bias0, void* __restrict__ C0,
           const bf16* __restrict__ A1, const bf16* __restrict__ B1,
           const float* __restrict__ bias1, void* __restrict__ C1,
           int nbm, int nbn, int K, int ldc)
{
    __shared__ __align__(16) char smem[131072];   // 2 x 64KB
    const int tid  = threadIdx.x;
    const int lane = tid & 63;
    const int wid  = tid >> 6;
    const int wm = wid >> 2, wn = wid & 3;
    const int r16 = lane & 15, kb = lane >> 4;

    int bid = blockIdx.x;
    {   // bijective XCD swizzle (m204)
        int nwg = gridDim.x;
        int q = nwg >> 3, r = nwg & 7;
        int xcd = bid & 7, idx = bid >> 3;
        bid = (xcd < r ? xcd * (q + 1) : r * (q + 1) + (xcd - r) * q) + idx;
    }
    const int npg = nbm * nbn;
    const int g   = bid / npg;
    const int lb  = bid - g * npg;
    const int bm = lb / nbn, bn = lb - bm * nbn;

    const bf16*  A    = g ? A1 : A0;
    const bf16*  Bw   = g ? B1 : B0;
    const float* bias = g ? bias1 : bias0;
    char* Cout = (char*)(g ? C1 : C0);

    const long row0 = (long)bm * 256;
    const int  col0 = bn * 256;
    const int  nt   = K >> 6;

    // staging sources (pre-swizzled; involution) + linear LDS dest offset
    const char* gA[2]; const char* gB[2];
    #pragma unroll
    for (int l = 0; l < 2; ++l) {
        const uint32_t S = (uint32_t)(l * 512 + tid) * 16;   // byte slot in 16KB plane
        const int r  = (int)(S >> 6);                        // plane row 0..255
        const int cb = (int)((S & 63) ^ ((uint32_t)((r >> 1) & 3) << 4));
        gA[l] = (const char*)A  + (row0 + r) * (long)K * 2 + cb;
        gB[l] = (const char*)Bw + (long)(col0 + r) * K * 2 + cb;
    }
    const uint32_t ldst = (uint32_t)(tid & ~63) * 16;        // + l*8192 + plane base

    // per-lane read base offsets within a plane (swizzled)
    const uint32_t swz  = ((uint32_t)(r16 >> 1) & 3u) << 4;
    const uint32_t aoff = (uint32_t)((wm * 128 + r16) * 64 + kb * 16) ^ swz;  // +4096 for row-half1, +fi*1024
    const uint32_t boff = (uint32_t)((wn * 64  + r16) * 64 + kb * 16) ^ swz;  // +fj*1024

    f32x4 acc[8][4];
    #pragma unroll
    for (int i = 0; i < 8; ++i)
        #pragma unroll
        for (int j = 0; j < 4; ++j)
            acc[i][j] = (f32x4){0.f, 0.f, 0.f, 0.f};

    // prologue: stage all 4 planes of tile 0 into buf0 (order A_k0,B_k0,A_k1,B_k1)
    __builtin_amdgcn_global_load_lds(AS1(gA[0]),      AS3(smem +     0 + ldst), 16, 0, 0);
    __builtin_amdgcn_global_load_lds(AS1(gA[1]),      AS3(smem +  8192 + ldst), 16, 0, 0);
    __builtin_amdgcn_global_load_lds(AS1(gB[0]),      AS3(smem + 32768 + ldst), 16, 0, 0);
    __builtin_amdgcn_global_load_lds(AS1(gB[1]),      AS3(smem + 40960 + ldst), 16, 0, 0);
    __builtin_amdgcn_global_load_lds(AS1(gA[0] + 64), AS3(smem + 16384 + ldst), 16, 0, 0);
    __builtin_amdgcn_global_load_lds(AS1(gA[1] + 64), AS3(smem + 24576 + ldst), 16, 0, 0);
    __builtin_amdgcn_global_load_lds(AS1(gB[0] + 64), AS3(smem + 49152 + ldst), 16, 0, 0);
    __builtin_amdgcn_global_load_lds(AS1(gB[1] + 64), AS3(smem + 57344 + ldst), 16, 0, 0);
    // gate planes A_k0,B_k0 of tile 0 (first 4 loads), then preload ph0 frags
    asm volatile("s_waitcnt vmcnt(4)\n\ts_barrier" ::: "memory");

    bf16x8 afA[4], afB[4], bv0[4], bv1[4];
    #pragma unroll
    for (int f = 0; f < 4; ++f) {
        afA[f] = *(const bf16x8*)(smem +     0 + aoff + f * 1024);   // A_k0 h0
        bv0[f] = *(const bf16x8*)(smem + 32768 + boff + f * 1024);   // B_k0
    }

#define MFMA16(AF, BV, IH)                                                              \
    __builtin_amdgcn_s_setprio(1);                                                      \
    _Pragma("unroll")                                                                   \
    for (int fi = 0; fi < 4; ++fi) {                                                    \
        acc[(IH)*4+fi][0] = __builtin_amdgcn_mfma_f32_16x16x32_bf16(AF[fi], BV[0], acc[(IH)*4+fi][0], 0, 0, 0); \
        acc[(IH)*4+fi][1] = __builtin_amdgcn_mfma_f32_16x16x32_bf16(AF[fi], BV[1], acc[(IH)*4+fi][1], 0, 0, 0); \
        acc[(IH)*4+fi][2] = __builtin_amdgcn_mfma_f32_16x16x32_bf16(AF[fi], BV[2], acc[(IH)*4+fi][2], 0, 0, 0); \
        acc[(IH)*4+fi][3] = __builtin_amdgcn_mfma_f32_16x16x32_bf16(AF[fi], BV[3], acc[(IH)*4+fi][3], 0, 0, 0); \
    }                                                                                   \
    __builtin_amdgcn_s_setprio(0);

    for (int t = 0; t < nt; ++t) {
        const char* pb = smem + (t & 1) * 65536;
        char*       pt = smem + ((t + 1) & 1) * 65536;
        const bool  st = (t + 1 < nt);
        const long  koff = (long)(t + 1) * 128;

        // ---- ph0: MFMA(afA,bv0)->acc[0..3]; read afB <- A_k0 h1; stage A_k0(t+1)
        if (st) {
            __builtin_amdgcn_global_load_lds(AS1(gA[0] + koff), AS3(pt +    0 + ldst), 16, 0, 0);
            __builtin_amdgcn_global_load_lds(AS1(gA[1] + koff), AS3(pt + 8192 + ldst), 16, 0, 0);
        }
        asm volatile("s_barrier" ::: "memory");
        #pragma unroll
        for (int f = 0; f < 4; ++f)
            afB[f] = *(const bf16x8*)(pb + 4096 + aoff + f * 1024);
        MFMA16(afA, bv0, 0)

        // ---- ph1: MFMA(afB,bv0)->acc[4..7]; read afA <- A_k1 h0, bv1 <- B_k1; stage B_k0(t+1)
        if (st) {
            __builtin_amdgcn_global_load_lds(AS1(gB[0] + koff), AS3(pt + 32768 + ldst), 16, 0, 0);
            __builtin_amdgcn_global_load_lds(AS1(gB[1] + koff), AS3(pt + 40960 + ldst), 16, 0, 0);
            asm volatile("s_waitcnt vmcnt(4)" ::: "memory");
        } else {
            asm volatile("s_waitcnt vmcnt(0)" ::: "memory");
        }
        asm volatile("s_barrier" ::: "memory");
        #pragma unroll
        for (int f = 0; f < 4; ++f) {
            afA[f] = *(const bf16x8*)(pb + 16384 + aoff + f * 1024);   // A_k1 h0
            bv1[f] = *(const bf16x8*)(pb + 49152 + boff + f * 1024);   // B_k1
        }
        MFMA16(afB, bv0, 1)

        // ---- ph2: MFMA(afA,bv1)->acc[0..3]; read afB <- A_k1 h1; stage A_k1(t+1)
        if (st) {
            __builtin_amdgcn_global_load_lds(AS1(gA[0] + koff + 64), AS3(pt + 16384 + ldst), 16, 0, 0);
            __builtin_amdgcn_global_load_lds(AS1(gA[1] + koff + 64), AS3(pt + 24576 + ldst), 16, 0, 0);
        }
        asm volatile("s_barrier" ::: "memory");
        #pragma unroll
        for (int f = 0; f < 4; ++f)
            afB[f] = *(const bf16x8*)(pb + 16384 + 4096 + aoff + f * 1024);
        MFMA16(afA, bv1, 0)

        // ---- ph3: MFMA(afB,bv1)->acc[4..7]; read afA,bv0 <- NEXT tile A_k0 h0,B_k0 (from pt); stage B_k1(t+1)
        if (st) {
            __builtin_amdgcn_global_load_lds(AS1(gB[0] + koff + 64), AS3(pt + 49152 + ldst), 16, 0, 0);
            __builtin_amdgcn_global_load_lds(AS1(gB[1] + koff + 64), AS3(pt + 57344 + ldst), 16, 0, 0);
            asm volatile("s_waitcnt vmcnt(4)" ::: "memory");
        }
        asm volatile("s_barrier" ::: "memory");
        if (st) {
            #pragma unroll
            for (int f = 0; f < 4; ++f) {
                afA[f] = *(const bf16x8*)(pt +     0 + aoff + f * 1024);   // A_k0(t+1) h0
                bv0[f] = *(const bf16x8*)(pt + 32768 + boff + f * 1024);   // B_k0(t+1)
            }
        }
        MFMA16(afB, bv1, 1)
    }
#undef MFMA16

    // epilogue: row = row0 + wm*128 + i*16 + (lane>>4)*4 + e ; col = col0 + wn*64 + j*16 + r16
    const int rb = (lane >> 4) * 4;
    #pragma unroll
    for (int i = 0; i < 8; ++i) {
        #pragma unroll
        for (int j = 0; j < 4; ++j) {
            const int cc = col0 + wn * 64 + j * 16 + r16;
            float badd = 0.f;
            if (MODE == 1) badd = bias[cc];
            #pragma unroll
            for (int e = 0; e < 4; ++e) {
                long row = row0 + wm * 128 + i * 16 + rb + e;
                float v = acc[i][j][e];
                if (MODE == 1) {
                    v += badd;
                    v = fmaxf(v, 0.f);
                    v = v * v;
                    ((bf16*)Cout)[row * ldc + cc] = __float2bfloat16(v);
                } else {
                    ((float*)Cout)[row * ldc + cc] = v;
                }
            }
        }
    }
}

// ---------------- glue: per-token gating / tiny einsums ----------------
// In:  g1,g2 [TOK][8][512] f32; Yl[:,0:4096]=x1 raw bf16; Yr[:,4096:8192]=x2 raw bf16
// Out: Yl = [x1*g1s | y12 | g1s]; Yr = [y21 | x2*g2s | g2s]  (all bf16)
#define GPAD 524   // 8-row pad: h-stride hits 8 distinct banks; 524*4%16==0
__global__ __launch_bounds__(256)
void glue(const float* __restrict__ g1, const float* __restrict__ g2,
          bf16* __restrict__ Yl, bf16* __restrict__ Yr)
{
    __shared__ __align__(16) float g1t[8 * GPAD];
    __shared__ __align__(16) float g2t[8 * GPAD];
    __shared__ float g1s[EE], g2s[EE];
    __shared__ float t1s[64], t2s[64];
    __shared__ float t1p[4][64], t2p[4][64];
    __shared__ __align__(16) bf16 x1t[FF], x2t[FF];

    const int t   = blockIdx.x;
    const int tid = threadIdx.x;
    const float* g1p = g1 + (size_t)t * FF;
    const float* g2p = g2 + (size_t)t * FF;
    bf16* ylp = Yl + (size_t)t * KCAT;
    bf16* yrp = Yr + (size_t)t * KCAT;

    #pragma unroll
    for (int c = 0; c < 4; ++c) {
        int idx4 = (c * 256 + tid) * 4;
        float4 v1 = *(const float4*)(g1p + idx4);
        float4 v2 = *(const float4*)(g2p + idx4);
        int h = idx4 >> 9, e = idx4 & 511;
        *(float4*)&g1t[h * GPAD + e] = v1;
        *(float4*)&g2t[h * GPAD + e] = v2;
    }
    #pragma unroll
    for (int c = 0; c < 2; ++c) {
        int idx8 = (c * 256 + tid) * 8;
        *(bf16x8*)&x1t[idx8] = *(const bf16x8*)(ylp + idx8);
        *(bf16x8*)&x2t[idx8] = *(const bf16x8*)(yrp + FF + idx8);
    }
    __syncthreads();

    #pragma unroll
    for (int c = 0; c < 2; ++c) {
        int e = c * 256 + tid;
        float s1 = 0.f, s2 = 0.f;
        #pragma unroll
        for (int h = 0; h < 8; ++h) { s1 += g1t[h * GPAD + e]; s2 += g2t[h * GPAD + e]; }
        g1s[e] = s1; g2s[e] = s2;
    }

    {   // t1[h,m] = sum_e x1[e,m]*g1[h,e] ; t2 likewise. 4-way partials.
        int o = tid & 63;
        int h = o & 7, m = o >> 3;
        int p = tid >> 6;
        float s1 = 0.f, s2 = 0.f;
        #pragma unroll 8
        for (int ii = 0; ii < 128; ++ii) {
            int e = p * 128 + ii;
            float xv1 = __bfloat162float(x1t[e * 8 + m]);
            float xv2 = __bfloat162float(x2t[e * 8 + m]);
            s1 += xv1 * g1t[h * GPAD + e];
            s2 += xv2 * g2t[h * GPAD + e];
        }
        t1p[p][o] = s1; t2p[p][o] = s2;
    }
    __syncthreads();
    if (tid < 64)       t1s[tid] = t1p[0][tid] + t1p[1][tid] + t1p[2][tid] + t1p[3][tid];
    else if (tid < 128) { int o = tid - 64; t2s[o] = t2p[0][o] + t2p[1][o] + t2p[2][o] + t2p[3][o]; }
    __syncthreads();

    #pragma unroll
    for (int c = 0; c < 2; ++c) {
        int f0 = (c * 256 + tid) * 8;
        int e  = f0 >> 3;
        float s1 = g1s[e], s2 = g2s[e];
        bf16x8 xa = *(const bf16x8*)&x1t[f0];
        bf16x8 xb = *(const bf16x8*)&x2t[f0];
        bf16x8 o1, o2;
        #pragma unroll
        for (int u = 0; u < 8; ++u) {
            o1[u] = (__bf16)((float)xa[u] * s1);
            o2[u] = (__bf16)((float)xb[u] * s2);
        }
        *(bf16x8*)(ylp + f0)      = o1;
        *(bf16x8*)(yrp + FF + f0) = o2;
    }
    #pragma unroll
    for (int c = 0; c < 2; ++c) {
        int f0 = (c * 256 + tid) * 8;
        int i  = f0 >> 3;
        bf16x8 o12v, o21v;
        #pragma unroll
        for (int m = 0; m < 8; ++m) {
            float s12 = 0.f, s21 = 0.f;
            #pragma unroll
            for (int h = 0; h < 8; ++h) {
                s12 += t2s[(m << 3) | h] * g1t[h * GPAD + i];
                s21 += t1s[(m << 3) | h] * g2t[h * GPAD + i];
            }
            o12v[m] = (__bf16)s12;
            o21v[m] = (__bf16)s21;
        }
        *(bf16x8*)(ylp + FF + f0) = o12v;
        *(bf16x8*)(yrp + f0)      = o21v;
    }
    {
        int e0 = tid * 2;
        ylp[2 * FF + e0]     = __float2bfloat16(g1s[e0]);
        ylp[2 * FF + e0 + 1] = __float2bfloat16(g1s[e0 + 1]);
        yrp[2 * FF + e0]     = __float2bfloat16(g2s[e0]);
        yrp[2 * FF + e0 + 1] = __float2bfloat16(g2s[e0 + 1]);
    }
}

// ---------------- launch ----------------

extern "C" void kernel_launch(void* const* d_in, const int* in_sizes, int n_in,
                              void* d_out, int out_size, void* d_ws, size_t ws_size,
                              hipStream_t stream) {
    const float* x    = (const float*)d_in[0];
    const float* g1   = (const float*)d_in[1];
    const float* g2   = (const float*)d_in[2];
    const float* u1_w = (const float*)d_in[3];
    const float* u1_b = (const float*)d_in[4];
    const float* u2_w = (const float*)d_in[5];
    const float* u2_b = (const float*)d_in[6];
    const float* v11  = (const float*)d_in[7];
    const float* v12  = (const float*)d_in[8];
    const float* v21  = (const float*)d_in[9];
    const float* v22  = (const float*)d_in[10];
    const float* b1   = (const float*)d_in[11];
    const float* b2   = (const float*)d_in[12];
    float* out = (float*)d_out;

    size_t off = 0;
    char* base = (char*)d_ws;
    auto take = [&](size_t bytes) { void* p = base + off; off += (bytes + 255) & ~(size_t)255; return p; };
    bf16* Xb  = (bf16*)take((size_t)TOK * DD * 2);
    bf16* U1b = (bf16*)take((size_t)FF * DD * 2);
    bf16* U2b = (bf16*)take((size_t)FF * DD * 2);
    bf16* Wl  = (bf16*)take((size_t)HALF * KCAT * 2);
    bf16* Wr  = (bf16*)take((size_t)HALF * KCAT * 2);
    bf16* Yl  = (bf16*)take((size_t)TOK * KCAT * 2);
    bf16* Yr  = (bf16*)take((size_t)TOK * KCAT * 2);

    // prep
    cvt_bf16<<<4096, 256, 0, stream>>>(x,    Xb,  TOK * DD / 4);
    cvt_bf16<<<2048, 256, 0, stream>>>(u1_w, U1b, FF * DD / 4);
    cvt_bf16<<<2048, 256, 0, stream>>>(u2_w, U2b, FF * DD / 4);
    pack_w<<<HALF, 256, 0, stream>>>(v11, v12, b1, Wl);
    pack_w<<<HALF, 256, 0, stream>>>(v21, v22, b2, Wr);

    // fused U-GEMMs: x1raw -> Yl[:,0:4096], x2raw -> Yr[:,4096:8192]  (relu^2, bf16)
    gemmP<1><<<2 * (TOK / 256) * (FF / 256), 512, 0, stream>>>(
        Xb, U1b, u1_b, Yl,
        Xb, U2b, u2_b, Yr + FF,
        TOK / 256, FF / 256, DD, KCAT);

    // gating / tiny einsums
    glue<<<TOK, 256, 0, stream>>>(g1, g2, Yl, Yr);

    // fused V-GEMMs: out[:,0:1024] = Yl @ Wl^T ; out[:,1024:2048] = Yr @ Wr^T  (fp32)
    gemmP<0><<<2 * (TOK / 256) * (HALF / 256), 512, 0, stream>>>(
        Yl, Wl, nullptr, out,
        Yr, Wr, nullptr, out + HALF,
        TOK / 256, HALF / 256, KCAT, DD);
}

// Round 7
// 678.887 us; speedup vs baseline: 1.2241x; 1.0207x over previous
//
#include <hip/hip_runtime.h>
#include <hip/hip_bf16.h>

// MonetMoVDE: B=4 T=2048 D=2048 H=8 E=512 M=8, F=4096, HALF=1024
#define TOK   8192   // B*T
#define DD    2048
#define FF    4096
#define EE    512
#define HALF  1024
#define KCAT  8704   // F + F + E  (concat K for V-GEMMs, 8704 = 136*64)

typedef __bf16 bf16x8 __attribute__((ext_vector_type(8)));
typedef __bf16 bf16x4 __attribute__((ext_vector_type(4)));
typedef float  f32x4  __attribute__((ext_vector_type(4)));
using bf16 = __hip_bfloat16;

#define AS1(p) ((const __attribute__((address_space(1))) void*)(p))
#define AS3(p) ((__attribute__((address_space(3))) void*)(p))

// ---------------- prep kernels ----------------

__global__ void cvt_bf16(const float* __restrict__ in, bf16* __restrict__ out, int n4) {
    int i = blockIdx.x * blockDim.x + threadIdx.x;
    int stride = gridDim.x * blockDim.x;
    for (; i < n4; i += stride) {
        float4 v = ((const float4*)in)[i];
        bf16x4 o;
        o[0] = (__bf16)v.x; o[1] = (__bf16)v.y; o[2] = (__bf16)v.z; o[3] = (__bf16)v.w;
        ((bf16x4*)out)[i] = o;
    }
}

// W [1024][8704] = [vA | vB | bT]   (vA,vB: [1024][4096] f32; bmat: [512][1024] f32)
__global__ void pack_w(const float* __restrict__ vA, const float* __restrict__ vB,
                       const float* __restrict__ bmat, bf16* __restrict__ W) {
    int n = blockIdx.x;
    const float* ra = vA + (size_t)n * FF;
    const float* rb = vB + (size_t)n * FF;
    bf16* w = W + (size_t)n * KCAT;
    for (int k = threadIdx.x; k < FF; k += 256) {
        w[k]      = __float2bfloat16(ra[k]);
        w[FF + k] = __float2bfloat16(rb[k]);
    }
    for (int e = threadIdx.x; e < EE; e += 256)
        w[2 * FF + e] = __float2bfloat16(bmat[(size_t)e * HALF + n]);
}

// ---------------- GEMM: C[m,n] = sum_k A[m,k] * Bw[n,k] ----------------
// m201-style schedule. 256x256 tile, BK=64, 8 waves (2Mx4N), 16x16x32 MFMA,
// per-wave C 128x64 (8 fi x 4 fj frags). LDS: 2 buffers x 64KB; buffer = 4
// chunks of 16KB: Ah0 @0, Ah1 @16K, Bh0 @32K, Bh1 @48K. Chunk = 128 rows x
// 128B (K=64), swizzle byte ^= ((row&7)<<4) (full-column XOR; read cohorts
// hit 8 distinct 16B slots -> 2 lanes/slot = conflict-free). Each wave reads
// ONLY chunk A-h(wm) and B-h(wn>>1) -> chunk slots free early, re-staged
// mid-tile for t+2. Phases per tile (quadrants of per-wave C x K=64):
//  ph0: read A fi0-3 (8) + B fj0-1 (4); stage Ah1(t+1)->other buf
//  ph1: read B fj2-3 (4)
//  ph2: read A fi4-7 (8); stage Bh0(t+2)->this buf
//  ph3: stage Ah0(t+2),Bh1(t+2)->this buf; vmcnt(6) gate (0 at tail)
// each phase: {reads; stages; barrier; lgkmcnt(0); sched_barrier; setprio(1);
// 16 MFMA; setprio(0); barrier}. Steady-state 3 chunks (6 loads) in flight.
// Fused dual-GEMM; MODE 0: fp32 store, MODE 1: relu(z+bias)^2 -> bf16 store.
template<int MODE>
__global__ __launch_bounds__(512, 1)
void gemmQ(const bf16* __restrict__ A0, const bf16* __restrict__ B0,
           const float* __restrict__ bias0, void* __restrict__ C0,
           const bf16* __restrict__ A1, const bf16* __restrict__ B1,
           const float* __restrict__ bias1, void* __restrict__ C1,
           int nbm, int nbn, int K, int ldc)
{
    __shared__ __align__(16) char smem[131072];   // 2 x 64KB
    const int tid  = threadIdx.x;
    const int lane = tid & 63;
    const int wid  = tid >> 6;
    const int wm = wid >> 2, wn = wid & 3;
    const int r16 = lane & 15, kb = lane >> 4;

    int bid = blockIdx.x;
    {   // bijective XCD swizzle (m204)
        int nwg = gridDim.x;
        int q = nwg >> 3, r = nwg & 7;
        int xcd = bid & 7, idx = bid >> 3;
        bid = (xcd < r ? xcd * (q + 1) : r * (q + 1) + (xcd - r) * q) + idx;
    }
    const int npg = nbm * nbn;
    const int g   = bid / npg;
    const int lb  = bid - g * npg;
    const int bm = lb / nbn, bn = lb - bm * nbn;

    const bf16*  A    = g ? A1 : A0;
    const bf16*  Bw   = g ? B1 : B0;
    const float* bias = g ? bias1 : bias0;
    char* Cout = (char*)(g ? C1 : C0);

    const long row0 = (long)bm * 256;
    const int  col0 = bn * 256;
    const int  nt   = K >> 6;

    // staging sources (pre-swizzled involution) for the 4 chunk types x 2 loads
    const char* sA[2][2]; const char* sB[2][2];
    #pragma unroll
    for (int l = 0; l < 2; ++l) {
        const uint32_t S = (uint32_t)(l * 512 + tid) * 16;   // byte slot in 16KB chunk
        const int r  = (int)(S >> 7);                        // chunk row 0..127
        const int cs = (int)((S & 127) ^ (((uint32_t)r & 7) << 4));
        sA[0][l] = (const char*)A  + (row0 + r)       * (long)K * 2 + cs;
        sA[1][l] = (const char*)A  + (row0 + 128 + r) * (long)K * 2 + cs;
        sB[0][l] = (const char*)Bw + (long)(col0 + r)       * K * 2 + cs;
        sB[1][l] = (const char*)Bw + (long)(col0 + 128 + r) * K * 2 + cs;
    }
    const uint32_t dst0 = (uint32_t)(tid & ~63) * 16;

#define STAGE(SP, BASE, KOFF)                                                            \
    __builtin_amdgcn_global_load_lds(AS1(SP[0] + (KOFF)), AS3(smem + (BASE) + dst0), 16, 0, 0); \
    __builtin_amdgcn_global_load_lds(AS1(SP[1] + (KOFF)), AS3(smem + (BASE) + 8192 + dst0), 16, 0, 0);

    // per-lane frag read offsets (swizzled, full-column XOR incl. kk bit)
    const uint32_t sw = ((uint32_t)(r16 & 7)) << 4;
    uint32_t co[2];
    co[0] = ((uint32_t)(kb * 16)) ^ sw;
    co[1] = ((uint32_t)(64 + kb * 16)) ^ sw;
    const uint32_t arow = (uint32_t)(r16 * 128);                       // + fi*2048
    const uint32_t brow = (uint32_t)(((wn & 1) * 64 + r16) * 128);     // + fj*2048
    const uint32_t Ab = (uint32_t)wm * 16384u;
    const uint32_t Bb = 32768u + ((uint32_t)(wn >> 1)) * 16384u;

    f32x4 acc[8][4];
    #pragma unroll
    for (int i = 0; i < 8; ++i)
        #pragma unroll
        for (int j = 0; j < 4; ++j)
            acc[i][j] = (f32x4){0.f, 0.f, 0.f, 0.f};

    // prologue: t0 full (8 loads) + t1 partial Ah0,Bh0,Bh1 (6 loads); gate+barrier
    STAGE(sA[0],     0, 0) STAGE(sB[0], 32768, 0) STAGE(sA[1], 16384, 0) STAGE(sB[1], 49152, 0)
    if (nt > 1) {
        STAGE(sA[0], 65536 +     0, 128) STAGE(sB[0], 65536 + 32768, 128) STAGE(sB[1], 65536 + 49152, 128)
        asm volatile("s_waitcnt vmcnt(6)" ::: "memory");
    } else {
        asm volatile("s_waitcnt vmcnt(0)" ::: "memory");
    }
    asm volatile("s_barrier" ::: "memory");

#define QUAD(RO, CO, AF, BV)                                                            \
    __builtin_amdgcn_s_setprio(1);                                                      \
    _Pragma("unroll")                                                                   \
    for (int f = 0; f < 4; ++f) {                                                       \
        _Pragma("unroll")                                                               \
        for (int j = 0; j < 2; ++j) {                                                   \
            acc[(RO)+f][(CO)+j] = __builtin_amdgcn_mfma_f32_16x16x32_bf16(AF[0][f], BV[0][j], acc[(RO)+f][(CO)+j], 0, 0, 0); \
            acc[(RO)+f][(CO)+j] = __builtin_amdgcn_mfma_f32_16x16x32_bf16(AF[1][f], BV[1][j], acc[(RO)+f][(CO)+j], 0, 0, 0); \
        }                                                                               \
    }                                                                                   \
    __builtin_amdgcn_s_setprio(0);

#define LGKM0()                                                                         \
    asm volatile("s_waitcnt lgkmcnt(0)" ::: "memory");                                  \
    __builtin_amdgcn_sched_barrier(0);

    bf16x8 af[2][4], bv[2][2], bv2[2][2];

    for (int t = 0; t < nt; ++t) {
        const uint32_t bo  = ((uint32_t)(t & 1)) << 16;
        const uint32_t bo1 = bo ^ 65536u;
        const char* pb = smem + bo;
        const long k1 = (long)(t + 1) * 128;
        const long k2 = (long)(t + 2) * 128;

        // ---- ph0: read A fi0-3 + B fj0-1; stage Ah1(t+1)
        #pragma unroll
        for (int kk = 0; kk < 2; ++kk) {
            #pragma unroll
            for (int f = 0; f < 4; ++f)
                af[kk][f] = *(const bf16x8*)(pb + Ab + arow + f * 2048 + co[kk]);
            #pragma unroll
            for (int j = 0; j < 2; ++j)
                bv[kk][j] = *(const bf16x8*)(pb + Bb + brow + j * 2048 + co[kk]);
        }
        if (t + 1 < nt) { STAGE(sA[1], bo1 + 16384, k1) }
        asm volatile("s_barrier" ::: "memory");
        LGKM0()
        QUAD(0, 0, af, bv)
        asm volatile("s_barrier" ::: "memory");

        // ---- ph1: read B fj2-3
        #pragma unroll
        for (int kk = 0; kk < 2; ++kk)
            #pragma unroll
            for (int j = 0; j < 2; ++j)
                bv2[kk][j] = *(const bf16x8*)(pb + Bb + brow + (j + 2) * 2048 + co[kk]);
        asm volatile("s_barrier" ::: "memory");
        LGKM0()
        QUAD(0, 2, af, bv2)
        asm volatile("s_barrier" ::: "memory");

        // ---- ph2: read A fi4-7; stage Bh0(t+2)
        #pragma unroll
        for (int kk = 0; kk < 2; ++kk)
            #pragma unroll
            for (int f = 0; f < 4; ++f)
                af[kk][f] = *(const bf16x8*)(pb + Ab + arow + (f + 4) * 2048 + co[kk]);
        if (t + 2 < nt) { STAGE(sB[0], bo + 32768, k2) }
        asm volatile("s_barrier" ::: "memory");
        LGKM0()
        QUAD(4, 0, af, bv)
        asm volatile("s_barrier" ::: "memory");

        // ---- ph3: stage Ah0(t+2),Bh1(t+2); vmcnt gate before closing barrier
        if (t + 2 < nt) {
            STAGE(sA[0], bo, k2) STAGE(sB[1], bo + 49152, k2)
            asm volatile("s_waitcnt vmcnt(6)" ::: "memory");
        } else if (t + 1 < nt) {
            asm volatile("s_waitcnt vmcnt(0)" ::: "memory");
        }
        asm volatile("s_barrier" ::: "memory");
        __builtin_amdgcn_sched_barrier(0);
        QUAD(4, 2, af, bv2)
        asm volatile("s_barrier" ::: "memory");
    }
#undef QUAD
#undef LGKM0
#undef STAGE

    // epilogue: row = row0 + wm*128 + i*16 + (lane>>4)*4 + e ; col = col0 + wn*64 + j*16 + r16
    const int rb = (lane >> 4) * 4;
    #pragma unroll
    for (int i = 0; i < 8; ++i) {
        #pragma unroll
        for (int j = 0; j < 4; ++j) {
            const int cc = col0 + wn * 64 + j * 16 + r16;
            float badd = 0.f;
            if (MODE == 1) badd = bias[cc];
            #pragma unroll
            for (int e = 0; e < 4; ++e) {
                long row = row0 + wm * 128 + i * 16 + rb + e;
                float v = acc[i][j][e];
                if (MODE == 1) {
                    v += badd;
                    v = fmaxf(v, 0.f);
                    v = v * v;
                    ((bf16*)Cout)[row * ldc + cc] = __float2bfloat16(v);
                } else {
                    ((float*)Cout)[row * ldc + cc] = v;
                }
            }
        }
    }
}

// ---------------- glue: per-token gating / tiny einsums ----------------
// In:  g1,g2 [TOK][8][512] f32; Yl[:,0:4096]=x1 raw bf16; Yr[:,4096:8192]=x2 raw bf16
// Out: Yl = [x1*g1s | y12 | g1s]; Yr = [y21 | x2*g2s | g2s]  (all bf16)
#define GPAD 524   // 8-row pad: h-stride hits 8 distinct banks; 524*4%16==0
__global__ __launch_bounds__(256)
void glue(const float* __restrict__ g1, const float* __restrict__ g2,
          bf16* __restrict__ Yl, bf16* __restrict__ Yr)
{
    __shared__ __align__(16) float g1t[8 * GPAD];
    __shared__ __align__(16) float g2t[8 * GPAD];
    __shared__ float g1s[EE], g2s[EE];
    __shared__ float t1s[64], t2s[64];
    __shared__ float t1p[4][64], t2p[4][64];
    __shared__ __align__(16) bf16 x1t[FF], x2t[FF];

    const int t   = blockIdx.x;
    const int tid = threadIdx.x;
    const float* g1p = g1 + (size_t)t * FF;
    const float* g2p = g2 + (size_t)t * FF;
    bf16* ylp = Yl + (size_t)t * KCAT;
    bf16* yrp = Yr + (size_t)t * KCAT;

    #pragma unroll
    for (int c = 0; c < 4; ++c) {
        int idx4 = (c * 256 + tid) * 4;
        float4 v1 = *(const float4*)(g1p + idx4);
        float4 v2 = *(const float4*)(g2p + idx4);
        int h = idx4 >> 9, e = idx4 & 511;
        *(float4*)&g1t[h * GPAD + e] = v1;
        *(float4*)&g2t[h * GPAD + e] = v2;
    }
    #pragma unroll
    for (int c = 0; c < 2; ++c) {
        int idx8 = (c * 256 + tid) * 8;
        *(bf16x8*)&x1t[idx8] = *(const bf16x8*)(ylp + idx8);
        *(bf16x8*)&x2t[idx8] = *(const bf16x8*)(yrp + FF + idx8);
    }
    __syncthreads();

    #pragma unroll
    for (int c = 0; c < 2; ++c) {
        int e = c * 256 + tid;
        float s1 = 0.f, s2 = 0.f;
        #pragma unroll
        for (int h = 0; h < 8; ++h) { s1 += g1t[h * GPAD + e]; s2 += g2t[h * GPAD + e]; }
        g1s[e] = s1; g2s[e] = s2;
    }

    {   // t1[h,m] = sum_e x1[e,m]*g1[h,e] ; t2 likewise. 4-way partials.
        int o = tid & 63;
        int h = o & 7, m = o >> 3;
        int p = tid >> 6;
        float s1 = 0.f, s2 = 0.f;
        #pragma unroll 8
        for (int ii = 0; ii < 128; ++ii) {
            int e = p * 128 + ii;
            float xv1 = __bfloat162float(x1t[e * 8 + m]);
            float xv2 = __bfloat162float(x2t[e * 8 + m]);
            s1 += xv1 * g1t[h * GPAD + e];
            s2 += xv2 * g2t[h * GPAD + e];
        }
        t1p[p][o] = s1; t2p[p][o] = s2;
    }
    __syncthreads();
    if (tid < 64)       t1s[tid] = t1p[0][tid] + t1p[1][tid] + t1p[2][tid] + t1p[3][tid];
    else if (tid < 128) { int o = tid - 64; t2s[o] = t2p[0][o] + t2p[1][o] + t2p[2][o] + t2p[3][o]; }
    __syncthreads();

    #pragma unroll
    for (int c = 0; c < 2; ++c) {
        int f0 = (c * 256 + tid) * 8;
        int e  = f0 >> 3;
        float s1 = g1s[e], s2 = g2s[e];
        bf16x8 xa = *(const bf16x8*)&x1t[f0];
        bf16x8 xb = *(const bf16x8*)&x2t[f0];
        bf16x8 o1, o2;
        #pragma unroll
        for (int u = 0; u < 8; ++u) {
            o1[u] = (__bf16)((float)xa[u] * s1);
            o2[u] = (__bf16)((float)xb[u] * s2);
        }
        *(bf16x8*)(ylp + f0)      = o1;
        *(bf16x8*)(yrp + FF + f0) = o2;
    }
    #pragma unroll
    for (int c = 0; c < 2; ++c) {
        int f0 = (c * 256 + tid) * 8;
        int i  = f0 >> 3;
        bf16x8 o12v, o21v;
        #pragma unroll
        for (int m = 0; m < 8; ++m) {
            float s12 = 0.f, s21 = 0.f;
            #pragma unroll
            for (int h = 0; h < 8; ++h) {
                s12 += t2s[(m << 3) | h] * g1t[h * GPAD + i];
                s21 += t1s[(m << 3) | h] * g2t[h * GPAD + i];
            }
            o12v[m] = (__bf16)s12;
            o21v[m] = (__bf16)s21;
        }
        *(bf16x8*)(ylp + FF + f0) = o12v;
        *(bf16x8*)(yrp + f0)      = o21v;
    }
    {
        int e0 = tid * 2;
        ylp[2 * FF + e0]     = __float2bfloat16(g1s[e0]);
        ylp[2 * FF + e0 + 1] = __float2bfloat16(g1s[e0 + 1]);
        yrp[2 * FF + e0]     = __float2bfloat16(g2s[e0]);
        yrp[2 * FF + e0 + 1] = __float2bfloat16(g2s[e0 + 1]);
    }
}

// ---------------- launch ----------------

extern "C" void kernel_launch(void* const* d_in, const int* in_sizes, int n_in,
                              void* d_out, int out_size, void* d_ws, size_t ws_size,
                              hipStream_t stream) {
    const float* x    = (const float*)d_in[0];
    const float* g1   = (const float*)d_in[1];
    const float* g2   = (const float*)d_in[2];
    const float* u1_w = (const float*)d_in[3];
    const float* u1_b = (const float*)d_in[4];
    const float* u2_w = (const float*)d_in[5];
    const float* u2_b = (const float*)d_in[6];
    const float* v11  = (const float*)d_in[7];
    const float* v12  = (const float*)d_in[8];
    const float* v21  = (const float*)d_in[9];
    const float* v22  = (const float*)d_in[10];
    const float* b1   = (const float*)d_in[11];
    const float* b2   = (const float*)d_in[12];
    float* out = (float*)d_out;

    size_t off = 0;
    char* base = (char*)d_ws;
    auto take = [&](size_t bytes) { void* p = base + off; off += (bytes + 255) & ~(size_t)255; return p; };
    bf16* Xb  = (bf16*)take((size_t)TOK * DD * 2);
    bf16* U1b = (bf16*)take((size_t)FF * DD * 2);
    bf16* U2b = (bf16*)take((size_t)FF * DD * 2);
    bf16* Wl  = (bf16*)take((size_t)HALF * KCAT * 2);
    bf16* Wr  = (bf16*)take((size_t)HALF * KCAT * 2);
    bf16* Yl  = (bf16*)take((size_t)TOK * KCAT * 2);
    bf16* Yr  = (bf16*)take((size_t)TOK * KCAT * 2);

    // prep
    cvt_bf16<<<4096, 256, 0, stream>>>(x,    Xb,  TOK * DD / 4);
    cvt_bf16<<<2048, 256, 0, stream>>>(u1_w, U1b, FF * DD / 4);
    cvt_bf16<<<2048, 256, 0, stream>>>(u2_w, U2b, FF * DD / 4);
    pack_w<<<HALF, 256, 0, stream>>>(v11, v12, b1, Wl);
    pack_w<<<HALF, 256, 0, stream>>>(v21, v22, b2, Wr);

    // fused U-GEMMs: x1raw -> Yl[:,0:4096], x2raw -> Yr[:,4096:8192]  (relu^2, bf16)
    gemmQ<1><<<2 * (TOK / 256) * (FF / 256), 512, 0, stream>>>(
        Xb, U1b, u1_b, Yl,
        Xb, U2b, u2_b, Yr + FF,
        TOK / 256, FF / 256, DD, KCAT);

    // gating / tiny einsums
    glue<<<TOK, 256, 0, stream>>>(g1, g2, Yl, Yr);

    // fused V-GEMMs: out[:,0:1024] = Yl @ Wl^T ; out[:,1024:2048] = Yr @ Wr^T  (fp32)
    gemmQ<0><<<2 * (TOK / 256) * (HALF / 256), 512, 0, stream>>>(
        Yl, Wl, nullptr, out,
        Yr, Wr, nullptr, out + HALF,
        TOK / 256, HALF / 256, KCAT, DD);
}